// Round 8
// baseline (32765.219 us; speedup 1.0000x reference)
//
#include <hip/hip_runtime.h>
#include <stdint.h>

// LSTM seq2seq (B=64, S=2048, H=512, L=2) as ONE persistent kernel, v8.
// = v7 (passed, 29.3ms) with the grid shrunk to match the tiny per-phase work:
//   * 64 WGs x 256 thr; WG owns 8 hidden cols -> 32 gate rows (2 N-tiles/wave).
//     Halves barrier arrivals, quarters poll pressure, halves LLC A-traffic.
//   * all 3 weight slices in LDS (96KB; gfx950 allows >64KB static).
//   * decoder B: Whh0.h0(t) issued BETWEEN arrive and poll (runs while waiting).
// Transport/layout/math identical to v7 (agent-scope relaxed atomics, sigma
// k-perm on both A and B sides, fc-as-broadcast-MFMA, fp32 cell state).

#define NWG   64
#define NTHR  256
#define SEQ   2048
#define NB    64
#define NH    512

typedef _Float16 half8v __attribute__((ext_vector_type(8)));
typedef float    f32x4  __attribute__((ext_vector_type(4)));

struct P {
  const float *x;
  const float *eWih0, *eWhh0, *ebih0, *ebhh0;
  const float *eWih1, *eWhh1, *ebih1, *ebhh1;
  const float *dWih0, *dWhh0, *dbih0, *dbhh0;
  const float *dWih1, *dWhh1, *dbih1, *dbhh1;
  const float *fcW, *fcb;
  float *out;
  unsigned short *H0, *H1;   // 2 parities x [ks4=0..63][m=0..63][8 half] = 64KB each
  unsigned *cnt;             // 8 counters, 128B apart (zeroed every launch)
};

__device__ __forceinline__ uint64_t ldg64(const uint64_t* p) {
  return __hip_atomic_load(p, __ATOMIC_RELAXED, __HIP_MEMORY_SCOPE_AGENT);
}
__device__ __forceinline__ void stg64(uint64_t* p, uint64_t v) {
  __hip_atomic_store(p, v, __ATOMIC_RELAXED, __HIP_MEMORY_SCOPE_AGENT);
}
__device__ __forceinline__ float sigf(float v)   { return 1.f / (1.f + __expf(-v)); }
__device__ __forceinline__ float tanhf_(float v) { return 2.f * sigf(2.f * v) - 1.f; }

__global__ __launch_bounds__(NTHR, 1) void lstm_persist(P p) {
  __shared__ half8v wlds[3][2][16][64];  // 96KB: slot0=Whh0, slot1=Wih1, slot2=Whh1
  __shared__ half8v fcw_c[16][4];        // fcW broadcast B-frags (sigma)
  __shared__ float  bias_lds[4][2][16];  // [e0,e1,d0,d1][nt][nn] (bih+bhh)
  __shared__ float  w0v_lds[2][2][16];   // Wih0 col [enc,dec][nt][nn]
  __shared__ float  c_lds[2][NB][8];     // fp32 cell state [lay][b][col]
  __shared__ float  h_tmp[2][NB][8];     // fp32 h' staging [lay][b][col]
  __shared__ float  fcb_s;

  const int wg   = blockIdx.x;
  const int tid  = threadIdx.x;
  const int lane = tid & 63;
  const int wv   = tid >> 6;
  const int Mb   = wv * 16;
  const int lo4  = lane >> 4;
  const int nn   = lane & 15;
  const int q    = nn >> 2, r = nn & 3;

  unsigned epoch = 0;

  // ---- split barrier: arrive (add) / wait (poll) so work can overlap ----
  auto arrive = [&]() {
    epoch++;
    __syncthreads();                     // drains vmcnt(0) per wave before s_barrier
    if (tid == 0)
      __hip_atomic_fetch_add(p.cnt + (wg & 7) * 32, 1u,
                             __ATOMIC_RELAXED, __HIP_MEMORY_SCOPE_AGENT);
  };
  auto wait = [&]() {
    if (tid < 8) {
      const unsigned tgt = 8u * epoch;
      while (__hip_atomic_load(p.cnt + tid * 32,
                               __ATOMIC_RELAXED, __HIP_MEMORY_SCOPE_AGENT) < tgt)
        __builtin_amdgcn_s_sleep(2);
    }
    __builtin_amdgcn_fence(__ATOMIC_ACQUIRE, "workgroup");
    __syncthreads();
  };
  auto gbar = [&]() { arrive(); wait(); };

  // -------- weight gather: global fp32 -> LDS fp16 B-frags (sigma) --------
  auto loadW = [&](int slot, const float *__restrict__ W) {
    for (int idx = tid; idx < 2 * 16 * 64; idx += NTHR) {
      const int nt = idx >> 10, ks = (idx >> 6) & 15, l = idx & 63;
      const int g = 8 * wg + 4 * nt + (l & 3) + 512 * ((l >> 2) & 3);
      const float *base = W + (size_t)g * NH + 32 * ks + 4 * (l >> 4);
      f32x4 wa, wb;
      __builtin_memcpy(&wa, base, 16);
      __builtin_memcpy(&wb, base + 16, 16);
      half8v h;
      h[0] = (_Float16)wa[0]; h[1] = (_Float16)wa[1];
      h[2] = (_Float16)wa[2]; h[3] = (_Float16)wa[3];
      h[4] = (_Float16)wb[0]; h[5] = (_Float16)wb[1];
      h[6] = (_Float16)wb[2]; h[7] = (_Float16)wb[3];
      wlds[slot][nt][ks][l] = h;
    }
  };

  // -------- A-fragment load: 32 x 8B agent-atomic, staged then packed --------
  auto ldA = [&](const unsigned short* Hb, half8v* A) {
    const uint64_t* bp = (const uint64_t*)Hb + (size_t)(Mb + nn) * 2 + lo4 * 128;
    uint64_t u0[16], u1[16];
#pragma unroll
    for (int ks = 0; ks < 16; ++ks) {
      u0[ks] = ldg64(bp + ks * 512);
      u1[ks] = ldg64(bp + ks * 512 + 1);
    }
#pragma unroll
    for (int ks = 0; ks < 16; ++ks) {
      union { uint64_t u[2]; half8v h; } T;
      T.u[0] = u0[ks]; T.u[1] = u1[ks];
      A[ks] = T.h;
    }
  };

  auto mm2 = [&](f32x4* acc2, const half8v* A, int slot) {
#pragma unroll
    for (int ks = 0; ks < 16; ++ks) {
      acc2[0] = __builtin_amdgcn_mfma_f32_16x16x32_f16(A[ks], wlds[slot][0][ks][lane], acc2[0], 0, 0, 0);
      acc2[1] = __builtin_amdgcn_mfma_f32_16x16x32_f16(A[ks], wlds[slot][1][ks][lane], acc2[1], 0, 0, 0);
    }
  };
  auto mmFC = [&](f32x4& afc, const half8v* A) {
#pragma unroll
    for (int ks = 0; ks < 16; ++ks)
      afc = __builtin_amdgcn_mfma_f32_16x16x32_f16(A[ks], fcw_c[ks][lo4], afc, 0, 0, 0);
  };

  // -------- gates -> (c,h'); h' fp32 into h_tmp[lay] --------
  auto cell2 = [&](const f32x4* acc2, int set, int ed, const float* xv4, int lay) {
#pragma unroll
    for (int nt = 0; nt < 2; ++nt) {
      float v[4];
#pragma unroll
      for (int j = 0; j < 4; ++j) {
        const float g = acc2[nt][j] + bias_lds[set][nt][nn] + xv4[j] * w0v_lds[ed][nt][nn];
        v[j] = (q == 2) ? tanhf_(g) : sigf(g);
      }
      float s4[4], s8[4], s12[4];
#pragma unroll
      for (int j = 0; j < 4; ++j) {
        s4[j]  = __shfl_xor(v[j], 4, 64);
        s8[j]  = __shfl_xor(v[j], 8, 64);
        s12[j] = __shfl_xor(v[j], 12, 64);
      }
      if (q == 0) {
#pragma unroll
        for (int j = 0; j < 4; ++j) {
          const int b = Mb + 4 * lo4 + j;
          const float co = c_lds[lay][b][4 * nt + r];
          const float cn = s4[j] * co + v[j] * s8[j];
          c_lds[lay][b][4 * nt + r] = cn;
          h_tmp[lay][b][4 * nt + r] = s12[j] * tanhf_(cn);
        }
      }
    }
  };

  // -------- publish: 128 lanes, one 8B piece each (4 aligned k's) --------
  const int pb   = tid >> 1;            // batch row
  const int pseg = tid & 1;             // which 4-col half
  const int pk0  = 8 * wg + 4 * pseg;
  const int prem = pk0 & 31;
  const size_t pidx = (size_t)(pk0 >> 5) * 512 + ((prem >> 2) & 3) * 128
                    + (size_t)pb * 2 + (prem >> 4);
  auto publish = [&](unsigned short* Hpar, int lay) {
    if (tid < 128) {
      union { uint64_t u; _Float16 h[4]; } cv;
#pragma unroll
      for (int e = 0; e < 4; ++e) cv.h[e] = (_Float16)h_tmp[lay][pb][4 * pseg + e];
      stg64((uint64_t*)Hpar + pidx, cv.u);
    }
  };

  // ================= init =================
  loadW(0, p.eWhh0); loadW(1, p.eWih1); loadW(2, p.eWhh1);
  if (tid < 128) {
    const int set = tid >> 5, nt = (tid >> 4) & 1, c = tid & 15;
    const int g = 8 * wg + 4 * nt + (c & 3) + 512 * (c >> 2);
    const float bi = (set == 0) ? p.ebih0[g] + p.ebhh0[g]
                   : (set == 1) ? p.ebih1[g] + p.ebhh1[g]
                   : (set == 2) ? p.dbih0[g] + p.dbhh0[g]
                                : p.dbih1[g] + p.dbhh1[g];
    bias_lds[set][nt][c] = bi;
  }
  if (tid < 64) {
    const int ed = tid >> 5, nt = (tid >> 4) & 1, c = tid & 15;
    const int g = 8 * wg + 4 * nt + (c & 3) + 512 * (c >> 2);
    w0v_lds[ed][nt][c] = ed ? p.dWih0[g] : p.eWih0[g];
  }
  if (tid < 64) {                       // fcW broadcast B-frag (sigma)
    const int ks = tid >> 2, l4 = tid & 3;
    half8v h;
#pragma unroll
    for (int j = 0; j < 4; ++j) {
      h[j]     = (_Float16)p.fcW[32 * ks + 4 * l4 + j];
      h[4 + j] = (_Float16)p.fcW[32 * ks + 4 * l4 + 16 + j];
    }
    fcw_c[ks][l4] = h;
  }
  if (tid == 0) fcb_s = p.fcb[0];
  for (int i = tid; i < 2 * NB * 8; i += NTHR) {
    (&c_lds[0][0][0])[i] = 0.f;
    (&h_tmp[0][0][0])[i] = 0.f;
  }
  __syncthreads();
  publish(p.H0 + 32768, 0);             // h0(-1)=0 in H0[1]
  publish(p.H1, 1);                     // h1(-1)=0 in H1[0]
  float xv[4];
#pragma unroll
  for (int j = 0; j < 4; ++j) xv[j] = p.x[(size_t)(Mb + 4 * lo4 + j) * SEQ];
  const float zv4[4] = {0.f, 0.f, 0.f, 0.f};
  gbar();

  // ================= encoder: L0(t) || L1(t-1), 1 barrier/phase =================
  for (int t = 0; t <= SEQ; ++t) {
    const int ri = (t + 1) & 1, wi = t & 1;
    const bool d0 = (t < SEQ), d1 = (t > 0);
    half8v A0[16], A1[16];
    ldA(p.H0 + ri * 32768, A0);                  // h0(t-1)
    if (d1) ldA(p.H1 + ri * 32768, A1);          // h1(t-2)
    f32x4 a0[2] = {{0.f,0.f,0.f,0.f},{0.f,0.f,0.f,0.f}};
    f32x4 a1[2] = {{0.f,0.f,0.f,0.f},{0.f,0.f,0.f,0.f}};
    if (d0) mm2(a0, A0, 0);                      // Whh0 . h0(t-1)
    if (d1) mm2(a1, A0, 1);                      // Wih1 . h0(t-1)
    if (d1) mm2(a1, A1, 2);                      // + Whh1 . h1(t-2)
    if (d0) cell2(a0, 0, 0, xv, 0);
    if (d1) cell2(a1, 1, 0, zv4, 1);
    if (t + 1 < SEQ) {
#pragma unroll
      for (int j = 0; j < 4; ++j) xv[j] = p.x[(size_t)(Mb + 4 * lo4 + j) * SEQ + (t + 1)];
    }
    __syncthreads();
    if (d0) publish(p.H0 + wi * 32768, 0);
    if (d1) publish(p.H1 + wi * 32768, 1);
    gbar();
  }
  // encoder leaves: h0_enc in H0[1], h1_enc in H1[0]

  // ================= enc -> dec transition =================
  loadW(0, p.dWhh0); loadW(1, p.dWih1); loadW(2, p.dWhh1);
  __syncthreads();
  f32x4 accPre0[2] = {{0.f,0.f,0.f,0.f},{0.f,0.f,0.f,0.f}};
  {
    half8v A[16];
    ldA(p.H0 + 32768, A);                        // h0_enc
    mm2(accPre0, A, 0);                          // dWhh0 . h0_enc
  }

  // ============ decoder: A(t)=fc+Whh1+cell0, B(t)=Wih1+cell1 [+Whh0 overlapped] ====
  for (int t = 0; t < SEQ; ++t) {
    f32x4 acc1c[2];
    { // ---- A(t): reads h1(t-1) in H1[t&1] ----
      half8v A[16];
      ldA(p.H1 + (t & 1) * 32768, A);
      f32x4 aP1[2] = {{0.f,0.f,0.f,0.f},{0.f,0.f,0.f,0.f}};
      f32x4 afc = {0.f, 0.f, 0.f, 0.f};
      mm2(aP1, A, 2);                            // Whh1 . h1(t-1)
      mmFC(afc, A);                              // fc(h1(t-1)) broadcast
      acc1c[0] = aP1[0]; acc1c[1] = aP1[1];
      float yv4[4];
#pragma unroll
      for (int j = 0; j < 4; ++j) yv4[j] = (t == 0) ? 0.f : (afc[j] + fcb_s);
      if (t > 0 && wg == 0 && nn == 0) {
#pragma unroll
        for (int j = 0; j < 4; ++j)
          p.out[(size_t)(Mb + 4 * lo4 + j) * SEQ + (t - 1)] = yv4[j];
      }
      cell2(accPre0, 2, 1, yv4, 0);              // h0(t)
      __syncthreads();
      publish(p.H0 + (t & 1) * 32768, 0);
      gbar();
    }
    { // ---- B(t): reads h0(t) in H0[t&1] ----
      half8v A[16];
      ldA(p.H0 + (t & 1) * 32768, A);
      mm2(acc1c, A, 1);                          // + Wih1 . h0(t)
      cell2(acc1c, 3, 1, zv4, 1);                // h1(t)
      __syncthreads();
      publish(p.H1 + ((t + 1) & 1) * 32768, 1);
      arrive();
      f32x4 a0n[2] = {{0.f,0.f,0.f,0.f},{0.f,0.f,0.f,0.f}};
      mm2(a0n, A, 0);                            // Whh0 . h0(t) — overlaps the wait
      wait();
      accPre0[0] = a0n[0]; accPre0[1] = a0n[1];
    }
  }

  // ================= epilogue: y(2047) = fc(h1(2047)) in H1[0] =================
  if (wg == 0) {
    half8v A[16];
    ldA(p.H1, A);
    f32x4 afc = {0.f, 0.f, 0.f, 0.f};
    mmFC(afc, A);
    if (nn == 0) {
#pragma unroll
      for (int j = 0; j < 4; ++j)
        p.out[(size_t)(Mb + 4 * lo4 + j) * SEQ + (SEQ - 1)] = afc[j] + fcb_s;
    }
  }
}

extern "C" void kernel_launch(void* const* d_in, const int* in_sizes, int n_in,
                              void* d_out, int out_size, void* d_ws, size_t ws_size,
                              hipStream_t stream) {
  (void)in_sizes; (void)n_in; (void)out_size; (void)ws_size;
  P p;
  p.x     = (const float*)d_in[0];
  p.eWih0 = (const float*)d_in[1];  p.eWhh0 = (const float*)d_in[2];
  p.ebih0 = (const float*)d_in[3];  p.ebhh0 = (const float*)d_in[4];
  p.eWih1 = (const float*)d_in[5];  p.eWhh1 = (const float*)d_in[6];
  p.ebih1 = (const float*)d_in[7];  p.ebhh1 = (const float*)d_in[8];
  p.dWih0 = (const float*)d_in[9];  p.dWhh0 = (const float*)d_in[10];
  p.dbih0 = (const float*)d_in[11]; p.dbhh0 = (const float*)d_in[12];
  p.dWih1 = (const float*)d_in[13]; p.dWhh1 = (const float*)d_in[14];
  p.dbih1 = (const float*)d_in[15]; p.dbhh1 = (const float*)d_in[16];
  p.fcW   = (const float*)d_in[17]; p.fcb   = (const float*)d_in[18];
  p.out   = (float*)d_out;

  p.H0  = (unsigned short*)d_ws;                 // 128 KB (2 parities x 64 KB)
  p.H1  = (unsigned short*)d_ws + 2 * 32768;     // 128 KB
  p.cnt = (unsigned*)((char*)d_ws + 262144);     // 8 x 128B counters

  // Zero the barrier counters every call (graph-capturable, replay-safe).
  hipMemsetAsync((char*)d_ws + 262144, 0, 1024, stream);

  lstm_persist<<<dim3(NWG), dim3(NTHR), 0, stream>>>(p);
}

// Round 9
// 32423.557 us; speedup vs baseline: 1.0105x; 1.0105x over previous
//
#include <hip/hip_runtime.h>
#include <stdint.h>

// LSTM seq2seq (B=64, S=2048, H=512, L=2), v9: batch-partitioned groups.
// 256 WGs x 256 thr = 8 groups (g=wg&7) x 32 WGs (sl=wg>>3, 16 hidden cols).
// Each group owns 8 batch samples end-to-end: private 16KB H buffers (M=8
// padded to 16) and a private 32-wide barrier (4 counter lines x 8 adds).
// Transport = PROVEN agent-scope relaxed atomics (v6/v7). Wave = gate q
// (B-frags per gate); gates exchanged via padded LDS planes (no shuffles,
// no v8 bank conflicts). Whh0 in LDS (64KB -> 2 WG/CU co-residency slack);
// Wih1/Whh1 in per-wave VGPRs; fc as broadcast-B MFMA. fp32 cell state.

#define NWG   256
#define NTHR  256
#define SEQ   2048
#define NH    512

typedef _Float16 half8v __attribute__((ext_vector_type(8)));
typedef float    f32x4  __attribute__((ext_vector_type(4)));

struct P {
  const float *x;
  const float *eWih0, *eWhh0, *ebih0, *ebhh0;
  const float *eWih1, *eWhh1, *ebih1, *ebhh1;
  const float *dWih0, *dWhh0, *dbih0, *dbhh0;
  const float *dWih1, *dWhh1, *dbih1, *dbhh1;
  const float *fcW, *fcb;
  float *out;
  unsigned short *H;   // 8 groups x {H0[2],H1[2]} x [64 ks4][16 m][8 e] fp16 (16KB each)
  unsigned *cnt;       // 32 lines x 128B (zeroed every launch)
};

__device__ __forceinline__ uint64_t ldg64(const uint64_t* p) {
  return __hip_atomic_load(p, __ATOMIC_RELAXED, __HIP_MEMORY_SCOPE_AGENT);
}
__device__ __forceinline__ void stg64(uint64_t* p, uint64_t v) {
  __hip_atomic_store(p, v, __ATOMIC_RELAXED, __HIP_MEMORY_SCOPE_AGENT);
}
__device__ __forceinline__ float sigf(float v)   { return 1.f / (1.f + __expf(-v)); }
__device__ __forceinline__ float tanhf_(float v) { return 2.f * sigf(2.f * v) - 1.f; }

__global__ __launch_bounds__(NTHR, 2) void lstm_persist(P p) {
  __shared__ half8v wlds[4][16][64];   // 64KB: Whh0 slice (enc, then dec), [q][ks][lane]
  __shared__ half8v fcw_c[16][4];      // fcW broadcast B-frags
  __shared__ float  gate_s[2][4][8][16]; // [lay][q][m][c] fp32 gate planes
  __shared__ float  bias_s[2][4][16];  // current-stage bih+bhh [lay][q][c]
  __shared__ float  w0_s[4][16];       // current-stage Wih0 col [q][c]
  __shared__ float  c_st[2][16][9];    // fp32 cell state [lay][c][m] (pad 9)
  __shared__ float  h_tmp[2][16][9];   // fp32 h' staging  [lay][c][m] (pad 9)
  __shared__ float  x_s[8], y_s[8];
  __shared__ float  fcb_s;

  const int wg   = blockIdx.x;
  const int g    = wg & 7;        // batch group: samples [8g, 8g+8)
  const int sl   = wg >> 3;       // hidden slice 0..31: cols [16sl, 16sl+16)
  const int tid  = threadIdx.x;
  const int lane = tid & 63;
  const int wv   = tid >> 6;      // wave = gate q (i,f,g,o)
  const int lo4  = lane >> 4;
  const int nn   = lane & 15;     // B: col c; A: row m = lane&15

  unsigned short* Hg = p.H + (size_t)g * 32768;
  unsigned short* H0p[2] = {Hg, Hg + 8192};
  unsigned short* H1p[2] = {Hg + 16384, Hg + 24576};
  unsigned epoch = 0;

  half8v w1[16], w2[16];          // per-wave VGPR B-frags: Wih1, Whh1 (own gate rows)

  // ---- private group barrier: 4 counter lines, 8 adds each ----
  auto arrive = [&]() {
    epoch++;
    __syncthreads();              // drains vmcnt(0) before s_barrier (proven idiom)
    if (tid == 0)
      __hip_atomic_fetch_add(p.cnt + (g * 4 + (sl & 3)) * 32, 1u,
                             __ATOMIC_RELAXED, __HIP_MEMORY_SCOPE_AGENT);
  };
  auto wait = [&]() {
    if (tid < 4) {
      const unsigned tgt = 8u * epoch;
      while (__hip_atomic_load(p.cnt + (g * 4 + tid) * 32,
                               __ATOMIC_RELAXED, __HIP_MEMORY_SCOPE_AGENT) < tgt)
        __builtin_amdgcn_s_sleep(2);
    }
    __builtin_amdgcn_fence(__ATOMIC_ACQUIRE, "workgroup");
    __syncthreads();
  };
  auto gbar = [&]() { arrive(); wait(); };

  // ---- weight gathers (sigma: k = 32ks + 8*lo4 + e on BOTH A and B sides) ----
  auto loadW = [&](const float* __restrict__ W) {       // Whh0 slice -> LDS
    for (int idx = tid; idx < 4096; idx += NTHR) {
      const int q = idx >> 10, ks = (idx >> 6) & 15, l = idx & 63;
      const int gr = 512 * q + 16 * sl + (l & 15);
      const float* base = W + (size_t)gr * NH + 32 * ks + 8 * (l >> 4);
      f32x4 wa, wb;
      __builtin_memcpy(&wa, base, 16);
      __builtin_memcpy(&wb, base + 4, 16);
      half8v h;
      h[0]=(_Float16)wa[0]; h[1]=(_Float16)wa[1]; h[2]=(_Float16)wa[2]; h[3]=(_Float16)wa[3];
      h[4]=(_Float16)wb[0]; h[5]=(_Float16)wb[1]; h[6]=(_Float16)wb[2]; h[7]=(_Float16)wb[3];
      wlds[q][ks][l] = h;
    }
  };
  auto loadWV = [&](half8v* w, const float* __restrict__ W) {   // own gate rows -> VGPR
    const int gr = 512 * wv + 16 * sl + nn;
    const float* base = W + (size_t)gr * NH + 8 * lo4;
#pragma unroll
    for (int ks = 0; ks < 16; ++ks) {
      f32x4 wa, wb;
      __builtin_memcpy(&wa, base + 32 * ks, 16);
      __builtin_memcpy(&wb, base + 32 * ks + 4, 16);
      half8v h;
      h[0]=(_Float16)wa[0]; h[1]=(_Float16)wa[1]; h[2]=(_Float16)wa[2]; h[3]=(_Float16)wa[3];
      h[4]=(_Float16)wb[0]; h[5]=(_Float16)wb[1]; h[6]=(_Float16)wb[2]; h[7]=(_Float16)wb[3];
      w[ks] = h;
    }
  };
  auto loadBias = [&](const float* bi0, const float* bh0, const float* bi1,
                      const float* bh1, const float* Wi0) {
    if (tid < 128) {
      const int lay = tid >> 6, q = (tid >> 4) & 3, c = tid & 15;
      const int gr = 512 * q + 16 * sl + c;
      bias_s[lay][q][c] = lay ? (bi1[gr] + bh1[gr]) : (bi0[gr] + bh0[gr]);
    }
    if (tid < 64) {
      const int q = tid >> 4, c = tid & 15;
      w0_s[q][c] = Wi0[512 * q + 16 * sl + c];
    }
  };

  // ---- A-frags: 16KB matrix [64 ks4][16 m][8 e]; rows m>=8 are memset zeros ----
  auto ldA = [&](const unsigned short* Hm, half8v* A) {
    const uint64_t* bp = (const uint64_t*)Hm + (size_t)(lane & 15) * 2;
#pragma unroll
    for (int ks = 0; ks < 16; ++ks) {
      const int i = (4 * ks + lo4) * 32;
      union { uint64_t u[2]; half8v h; } T;
      T.u[0] = ldg64(bp + i);
      T.u[1] = ldg64(bp + i + 1);
      A[ks] = T.h;
    }
  };

  auto mmL = [&](f32x4& a, const half8v* A) {           // LDS B (Whh0)
#pragma unroll
    for (int ks = 0; ks < 16; ++ks)
      a = __builtin_amdgcn_mfma_f32_16x16x32_f16(A[ks], wlds[wv][ks][lane], a, 0, 0, 0);
  };
  auto mmV = [&](f32x4& a, const half8v* A, const half8v* w) {  // VGPR B
#pragma unroll
    for (int ks = 0; ks < 16; ++ks)
      a = __builtin_amdgcn_mfma_f32_16x16x32_f16(A[ks], w[ks], a, 0, 0, 0);
  };
  auto mmFC = [&](f32x4& a, const half8v* A) {
#pragma unroll
    for (int ks = 0; ks < 16; ++ks)
      a = __builtin_amdgcn_mfma_f32_16x16x32_f16(A[ks], fcw_c[ks][lo4], a, 0, 0, 0);
  };

  // D layout: col = lane&15 (c), row m = 4*lo4+j (real m<8 -> lo4<2)
  auto gwrite = [&](int lay, const f32x4& acc) {
    if (lo4 < 2) {
#pragma unroll
      for (int j = 0; j < 4; ++j) gate_s[lay][wv][4 * lo4 + j][nn] = acc[j];
    }
  };
  auto cellOne = [&](int lay, const float* inp8) {
    if (tid < 128) {
      const int c = tid & 15, m = tid >> 4;
      float g0 = gate_s[lay][0][m][c] + bias_s[lay][0][c];
      float g1 = gate_s[lay][1][m][c] + bias_s[lay][1][c];
      float g2 = gate_s[lay][2][m][c] + bias_s[lay][2][c];
      float g3 = gate_s[lay][3][m][c] + bias_s[lay][3][c];
      if (lay == 0) {
        const float xm = inp8[m];
        g0 += xm * w0_s[0][c]; g1 += xm * w0_s[1][c];
        g2 += xm * w0_s[2][c]; g3 += xm * w0_s[3][c];
      }
      const float i = sigf(g0), f = sigf(g1), gg = tanhf_(g2), o = sigf(g3);
      const float cn = f * c_st[lay][c][m] + i * gg;
      c_st[lay][c][m] = cn;
      h_tmp[lay][c][m] = o * tanhf_(cn);
    }
  };
  auto cellsEnc = [&](bool d0, bool d1) {
    const int lay = tid >> 7, u = tid & 127, c = u & 15, m = u >> 4;
    if (lay ? d1 : d0) {
      float g0 = gate_s[lay][0][m][c] + bias_s[lay][0][c];
      float g1 = gate_s[lay][1][m][c] + bias_s[lay][1][c];
      float g2 = gate_s[lay][2][m][c] + bias_s[lay][2][c];
      float g3 = gate_s[lay][3][m][c] + bias_s[lay][3][c];
      if (lay == 0) {
        const float xm = x_s[m];
        g0 += xm * w0_s[0][c]; g1 += xm * w0_s[1][c];
        g2 += xm * w0_s[2][c]; g3 += xm * w0_s[3][c];
      }
      const float i = sigf(g0), f = sigf(g1), gg = tanhf_(g2), o = sigf(g3);
      const float cn = f * c_st[lay][c][m] + i * gg;
      c_st[lay][c][m] = cn;
      h_tmp[lay][c][m] = o * tanhf_(cn);
    }
  };
  // publish own 16 cols x 8 samples (256B) into sigma layout
  auto publish = [&](int lay, unsigned short* Hpar) {
    if (tid < 32) {
      const int k4 = tid >> 4, m = (tid >> 1) & 7, seg = tid & 1;
      union { uint64_t u; _Float16 h[4]; } cv;
#pragma unroll
      for (int z = 0; z < 4; ++z)
        cv.h[z] = (_Float16)h_tmp[lay][8 * k4 + 4 * seg + z][m];
      stg64((uint64_t*)Hpar + ((size_t)(2 * sl + k4) * 16 + m) * 2 + seg, cv.u);
    }
  };

  // ================= init =================
  loadW(p.eWhh0);
  loadWV(w1, p.eWih1);
  loadWV(w2, p.eWhh1);
  loadBias(p.ebih0, p.ebhh0, p.ebih1, p.ebhh1, p.eWih0);
  if (tid < 64) {                 // fcW broadcast B-frag (same sigma)
    const int ks = tid >> 2, l4 = tid & 3;
    half8v h;
#pragma unroll
    for (int e = 0; e < 8; ++e) h[e] = (_Float16)p.fcW[32 * ks + 8 * l4 + e];
    fcw_c[ks][l4] = h;
  }
  if (tid == 0) fcb_s = p.fcb[0];
  for (int i = tid; i < 2 * 16 * 9; i += NTHR) {
    (&c_st[0][0][0])[i] = 0.f;
    (&h_tmp[0][0][0])[i] = 0.f;
  }
  // h0(-1)=0 (H0p[1]) and h1(-1)=0 (H1p[0]) come from the launch memset.

  // ================= encoder: L0(t) || L1(t-1), 1 barrier/slot =================
  for (int t = 0; t <= SEQ; ++t) {
    const int ri = (t + 1) & 1, wi = t & 1;
    const bool d0 = (t < SEQ), d1 = (t > 0);
    if (tid < 8 && d0) x_s[tid] = p.x[(size_t)(8 * g + tid) * SEQ + t];
    half8v A[16];
    f32x4 a0 = {0.f, 0.f, 0.f, 0.f}, a1 = {0.f, 0.f, 0.f, 0.f};
    ldA(H0p[ri], A);                  // h0(t-1)
    if (d0) mmL(a0, A);               // Whh0 . h0(t-1)
    if (d1) mmV(a1, A, w1);           // Wih1 . h0(t-1)
    if (d1) { ldA(H1p[ri], A); mmV(a1, A, w2); }  // + Whh1 . h1(t-2)
    if (d0) gwrite(0, a0);
    if (d1) gwrite(1, a1);
    __syncthreads();
    cellsEnc(d0, d1);
    __syncthreads();
    if (d0) publish(0, H0p[wi]);
    if (d1) publish(1, H1p[wi]);
    gbar();
  }
  // leaves: h0_enc(2047) in H0p[1], h1_enc(2047) in H1p[0]

  // ================= enc -> dec transition =================
  loadW(p.dWhh0);
  loadWV(w1, p.dWih1);
  loadWV(w2, p.dWhh1);
  loadBias(p.dbih0, p.dbhh0, p.dbih1, p.dbhh1, p.dWih0);
  __syncthreads();
  f32x4 accPre0 = {0.f, 0.f, 0.f, 0.f};
  {
    half8v A[16];
    ldA(H0p[1], A);                   // h0_enc
    mmL(accPre0, A);                  // dWhh0 . h0_enc
  }

  // ============ decoder: A(t)=fc+Whh1+cell0, B(t)=Wih1+cell1 [+Whh0 in wait] ====
  f32x4 aP1 = {0.f, 0.f, 0.f, 0.f};
  for (int t = 0; t < SEQ; ++t) {
    { // ---- A(t): reads h1(t-1) in H1p[t&1] ----
      half8v A[16];
      ldA(H1p[t & 1], A);
      f32x4 a = {0.f, 0.f, 0.f, 0.f};
      mmV(a, A, w2);                  // Whh1 . h1(t-1)
      aP1 = a;
      if (wv == 0) {                  // y(t-1) = fc(h1(t-1)), group-redundant-free
        f32x4 afc = {0.f, 0.f, 0.f, 0.f};
        mmFC(afc, A);
        if (nn == 0 && lo4 < 2) {
#pragma unroll
          for (int j = 0; j < 4; ++j)
            y_s[4 * lo4 + j] = (t == 0) ? 0.f : (afc[j] + fcb_s);
        }
      }
      gwrite(0, accPre0);             // Whh0 . h0(t-1) from previous B
      __syncthreads();
      cellOne(0, y_s);                // h0(t)
      if (t > 0 && sl == 0 && tid < 8)
        p.out[(size_t)(8 * g + tid) * SEQ + (t - 1)] = y_s[tid];
      __syncthreads();
      publish(0, H0p[t & 1]);
      gbar();
    }
    { // ---- B(t): reads h0(t) in H0p[t&1] ----
      half8v A[16];
      ldA(H0p[t & 1], A);
      mmV(aP1, A, w1);                // + Wih1 . h0(t)
      gwrite(1, aP1);
      __syncthreads();
      cellOne(1, nullptr);            // h1(t)
      __syncthreads();
      publish(1, H1p[(t + 1) & 1]);
      arrive();
      f32x4 a0n = {0.f, 0.f, 0.f, 0.f};
      mmL(a0n, A);                    // Whh0 . h0(t) — overlaps the wait
      wait();
      accPre0 = a0n;
    }
  }

  // ================= epilogue: y(2047) = fc(h1(2047)) in H1p[0] =================
  if (sl == 0) {
    half8v A[16];
    ldA(H1p[0], A);
    if (wv == 0) {
      f32x4 afc = {0.f, 0.f, 0.f, 0.f};
      mmFC(afc, A);
      if (nn == 0 && lo4 < 2) {
#pragma unroll
        for (int j = 0; j < 4; ++j) y_s[4 * lo4 + j] = afc[j] + fcb_s;
      }
    }
    __syncthreads();
    if (tid < 8) p.out[(size_t)(8 * g + tid) * SEQ + (SEQ - 1)] = y_s[tid];
  }
}

extern "C" void kernel_launch(void* const* d_in, const int* in_sizes, int n_in,
                              void* d_out, int out_size, void* d_ws, size_t ws_size,
                              hipStream_t stream) {
  (void)in_sizes; (void)n_in; (void)out_size; (void)ws_size;
  P p;
  p.x     = (const float*)d_in[0];
  p.eWih0 = (const float*)d_in[1];  p.eWhh0 = (const float*)d_in[2];
  p.ebih0 = (const float*)d_in[3];  p.ebhh0 = (const float*)d_in[4];
  p.eWih1 = (const float*)d_in[5];  p.eWhh1 = (const float*)d_in[6];
  p.ebih1 = (const float*)d_in[7];  p.ebhh1 = (const float*)d_in[8];
  p.dWih0 = (const float*)d_in[9];  p.dWhh0 = (const float*)d_in[10];
  p.dbih0 = (const float*)d_in[11]; p.dbhh0 = (const float*)d_in[12];
  p.dWih1 = (const float*)d_in[13]; p.dWhh1 = (const float*)d_in[14];
  p.dbih1 = (const float*)d_in[15]; p.dbhh1 = (const float*)d_in[16];
  p.fcW   = (const float*)d_in[17]; p.fcb   = (const float*)d_in[18];
  p.out   = (float*)d_out;

  p.H   = (unsigned short*)d_ws;                 // 8 groups x 64 KB = 512 KB
  p.cnt = (unsigned*)((char*)d_ws + 524288);     // 32 x 128 B counter lines

  // Zero H (h(-1)=0 + zero pad rows m>=8) and counters every launch
  // (graph-capturable, replay-safe).
  hipMemsetAsync(d_ws, 0, 524288 + 4096, stream);

  lstm_persist<<<dim3(NWG), dim3(NTHR), 0, stream>>>(p);
}

// Round 10
// 27537.234 us; speedup vs baseline: 1.1899x; 1.1774x over previous
//
#include <hip/hip_runtime.h>
#include <stdint.h>

// LSTM seq2seq (B=64, S=2048, H=512, L=2), v10 = v9 (passed, 32.4ms) with the
// phase-latency floor attacked:
//  * two-stage wait: wave0 tight-polls group counters -> LDS done flag;
//    waves1-3 BURN dependent VALU until released (keeps DVFS at boost,
//    removes s_sleep wakeup latency from the detect path).
//  * Whh1 moved VGPR->LDS (v9 spilled: 128 VGPR count with 128 regs of
//    weights live is impossible without scratch reloads in the phase loop).
//  * arrive spread over 8 counter lines x 4 adders (halves RMW serialization).
//  * gate_s padded [8][17] (v9: 6.7e7 bank-conflict cycles).
// Topology/transport/math identical to v9: 8 groups (g=wg&7) x 32 WGs
// (sl=wg>>3, 16 cols), private 16KB H buffers, agent-scope relaxed atomics.

#define NWG   256
#define NTHR  256
#define SEQ   2048
#define NH    512

typedef _Float16 half8v __attribute__((ext_vector_type(8)));
typedef float    f32x4  __attribute__((ext_vector_type(4)));

struct P {
  const float *x;
  const float *eWih0, *eWhh0, *ebih0, *ebhh0;
  const float *eWih1, *eWhh1, *ebih1, *ebhh1;
  const float *dWih0, *dWhh0, *dbih0, *dbhh0;
  const float *dWih1, *dWhh1, *dbih1, *dbhh1;
  const float *fcW, *fcb;
  float *out;
  unsigned short *H;   // 8 groups x {H0[2],H1[2]} x [64 ks4][16 m][8 e] fp16
  unsigned *cnt;       // 8 groups x 8 lines x 128B (zeroed every launch)
};

__device__ __forceinline__ uint64_t ldg64(const uint64_t* p) {
  return __hip_atomic_load(p, __ATOMIC_RELAXED, __HIP_MEMORY_SCOPE_AGENT);
}
__device__ __forceinline__ void stg64(uint64_t* p, uint64_t v) {
  __hip_atomic_store(p, v, __ATOMIC_RELAXED, __HIP_MEMORY_SCOPE_AGENT);
}
__device__ __forceinline__ float sigf(float v)   { return 1.f / (1.f + __expf(-v)); }
__device__ __forceinline__ float tanhf_(float v) { return 2.f * sigf(2.f * v) - 1.f; }

__global__ __launch_bounds__(NTHR, 1) void lstm_persist(P p) {
  __shared__ half8v wlds0[4][16][64];  // 64KB Whh0 slice [q][ks][lane]
  __shared__ half8v wlds2[4][16][64];  // 64KB Whh1 slice [q][ks][lane]
  __shared__ half8v fcw_c[16][4];      // fcW broadcast B-frags
  __shared__ float  gate_s[2][4][8][17]; // [lay][q][m][c] padded
  __shared__ float  bias_s[2][4][16];  // current-stage bih+bhh [lay][q][c]
  __shared__ float  w0_s[4][16];       // current-stage Wih0 col [q][c]
  __shared__ float  c_st[2][16][9];    // fp32 cell state [lay][c][m]
  __shared__ float  h_tmp[2][16][9];   // fp32 h' staging  [lay][c][m]
  __shared__ float  x_s[8], y_s[8];
  __shared__ float  fcb_s;
  __shared__ unsigned done_s;

  const int wg   = blockIdx.x;
  const int g    = wg & 7;        // batch group: samples [8g, 8g+8)
  const int sl   = wg >> 3;       // hidden slice 0..31: cols [16sl, 16sl+16)
  const int tid  = threadIdx.x;
  const int lane = tid & 63;
  const int wv   = tid >> 6;      // wave = gate q (i,f,g,o)
  const int lo4  = lane >> 4;
  const int nn   = lane & 15;

  unsigned short* Hg = p.H + (size_t)g * 32768;
  unsigned short* H0p[2] = {Hg, Hg + 8192};
  unsigned short* H1p[2] = {Hg + 16384, Hg + 24576};
  unsigned epoch = 0;

  half8v w1[16];                  // Wih1 own-gate-rows B-frags (64 VGPR)

  // ---- private group barrier: 8 lines x 4 adders; two-stage burn wait ----
  auto arrive = [&]() {
    epoch++;
    __syncthreads();              // drains vmcnt(0) before s_barrier
    if (tid == 0)
      __hip_atomic_fetch_add(p.cnt + (g * 8 + (sl & 7)) * 32, 1u,
                             __ATOMIC_RELAXED, __HIP_MEMORY_SCOPE_AGENT);
  };
  auto wait = [&]() {
    if (wv == 0) {
      if (lane < 8) {
        const unsigned tgt = 4u * epoch;
        while (__hip_atomic_load(p.cnt + (g * 8 + lane) * 32,
                                 __ATOMIC_RELAXED, __HIP_MEMORY_SCOPE_AGENT) < tgt) {}
      }
      if (lane == 0)
        __hip_atomic_store(&done_s, epoch, __ATOMIC_RELEASE,
                           __HIP_MEMORY_SCOPE_WORKGROUP);
    } else {
      unsigned dummy = tid;
      while (__hip_atomic_load(&done_s, __ATOMIC_ACQUIRE,
                               __HIP_MEMORY_SCOPE_WORKGROUP) != epoch) {
#pragma unroll
        for (int i = 0; i < 32; ++i)
          asm volatile("v_add_u32 %0, %0, 1" : "+v"(dummy));   // keep SIMD busy
      }
      asm volatile("" :: "v"(dummy));
    }
    __builtin_amdgcn_fence(__ATOMIC_ACQUIRE, "workgroup");
    __syncthreads();
  };
  auto gbar = [&]() { arrive(); wait(); };

  // ---- weight gathers (sigma: k = 32ks + 8*lo4 + e on BOTH A and B sides) ----
  auto loadW = [&](half8v (*wl)[16][64], const float* __restrict__ W) {
    for (int idx = tid; idx < 4096; idx += NTHR) {
      const int q = idx >> 10, ks = (idx >> 6) & 15, l = idx & 63;
      const int gr = 512 * q + 16 * sl + (l & 15);
      const float* base = W + (size_t)gr * NH + 32 * ks + 8 * (l >> 4);
      f32x4 wa, wb;
      __builtin_memcpy(&wa, base, 16);
      __builtin_memcpy(&wb, base + 4, 16);
      half8v h;
      h[0]=(_Float16)wa[0]; h[1]=(_Float16)wa[1]; h[2]=(_Float16)wa[2]; h[3]=(_Float16)wa[3];
      h[4]=(_Float16)wb[0]; h[5]=(_Float16)wb[1]; h[6]=(_Float16)wb[2]; h[7]=(_Float16)wb[3];
      wl[q][ks][l] = h;
    }
  };
  auto loadWV = [&](half8v* w, const float* __restrict__ W) {
    const int gr = 512 * wv + 16 * sl + nn;
    const float* base = W + (size_t)gr * NH + 8 * lo4;
#pragma unroll
    for (int ks = 0; ks < 16; ++ks) {
      f32x4 wa, wb;
      __builtin_memcpy(&wa, base + 32 * ks, 16);
      __builtin_memcpy(&wb, base + 32 * ks + 4, 16);
      half8v h;
      h[0]=(_Float16)wa[0]; h[1]=(_Float16)wa[1]; h[2]=(_Float16)wa[2]; h[3]=(_Float16)wa[3];
      h[4]=(_Float16)wb[0]; h[5]=(_Float16)wb[1]; h[6]=(_Float16)wb[2]; h[7]=(_Float16)wb[3];
      w[ks] = h;
    }
  };
  auto loadBias = [&](const float* bi0, const float* bh0, const float* bi1,
                      const float* bh1, const float* Wi0) {
    if (tid < 128) {
      const int lay = tid >> 6, q = (tid >> 4) & 3, c = tid & 15;
      const int gr = 512 * q + 16 * sl + c;
      bias_s[lay][q][c] = lay ? (bi1[gr] + bh1[gr]) : (bi0[gr] + bh0[gr]);
    }
    if (tid < 64) {
      const int q = tid >> 4, c = tid & 15;
      w0_s[q][c] = Wi0[512 * q + 16 * sl + c];
    }
  };

  // ---- A-frags: [64 ks4][16 m][8 e]; rows m>=8 stay memset-zero ----
  auto ldA = [&](const unsigned short* Hm, half8v* A) {
    const uint64_t* bp = (const uint64_t*)Hm + (size_t)(lane & 15) * 2;
#pragma unroll
    for (int ks = 0; ks < 16; ++ks) {
      const int i = (4 * ks + lo4) * 32;
      union { uint64_t u[2]; half8v h; } T;
      T.u[0] = ldg64(bp + i);
      T.u[1] = ldg64(bp + i + 1);
      A[ks] = T.h;
    }
  };

  auto mmL = [&](f32x4& a, const half8v* A, half8v (*wl)[16][64]) {
#pragma unroll
    for (int ks = 0; ks < 16; ++ks)
      a = __builtin_amdgcn_mfma_f32_16x16x32_f16(A[ks], wl[wv][ks][lane], a, 0, 0, 0);
  };
  auto mmV = [&](f32x4& a, const half8v* A, const half8v* w) {
#pragma unroll
    for (int ks = 0; ks < 16; ++ks)
      a = __builtin_amdgcn_mfma_f32_16x16x32_f16(A[ks], w[ks], a, 0, 0, 0);
  };
  auto mmFC = [&](f32x4& a, const half8v* A) {
#pragma unroll
    for (int ks = 0; ks < 16; ++ks)
      a = __builtin_amdgcn_mfma_f32_16x16x32_f16(A[ks], fcw_c[ks][lo4], a, 0, 0, 0);
  };

  auto gwrite = [&](int lay, const f32x4& acc) {
    if (lo4 < 2) {
#pragma unroll
      for (int j = 0; j < 4; ++j) gate_s[lay][wv][4 * lo4 + j][nn] = acc[j];
    }
  };
  auto cellOne = [&](int lay, const float* inp8) {
    if (tid < 128) {
      const int c = tid & 15, m = tid >> 4;
      float g0 = gate_s[lay][0][m][c] + bias_s[lay][0][c];
      float g1 = gate_s[lay][1][m][c] + bias_s[lay][1][c];
      float g2 = gate_s[lay][2][m][c] + bias_s[lay][2][c];
      float g3 = gate_s[lay][3][m][c] + bias_s[lay][3][c];
      if (lay == 0) {
        const float xm = inp8[m];
        g0 += xm * w0_s[0][c]; g1 += xm * w0_s[1][c];
        g2 += xm * w0_s[2][c]; g3 += xm * w0_s[3][c];
      }
      const float i = sigf(g0), f = sigf(g1), gg = tanhf_(g2), o = sigf(g3);
      const float cn = f * c_st[lay][c][m] + i * gg;
      c_st[lay][c][m] = cn;
      h_tmp[lay][c][m] = o * tanhf_(cn);
    }
  };
  auto cellsEnc = [&](bool d0, bool d1) {
    const int lay = tid >> 7, u = tid & 127, c = u & 15, m = u >> 4;
    if (lay ? d1 : d0) {
      float g0 = gate_s[lay][0][m][c] + bias_s[lay][0][c];
      float g1 = gate_s[lay][1][m][c] + bias_s[lay][1][c];
      float g2 = gate_s[lay][2][m][c] + bias_s[lay][2][c];
      float g3 = gate_s[lay][3][m][c] + bias_s[lay][3][c];
      if (lay == 0) {
        const float xm = x_s[m];
        g0 += xm * w0_s[0][c]; g1 += xm * w0_s[1][c];
        g2 += xm * w0_s[2][c]; g3 += xm * w0_s[3][c];
      }
      const float i = sigf(g0), f = sigf(g1), gg = tanhf_(g2), o = sigf(g3);
      const float cn = f * c_st[lay][c][m] + i * gg;
      c_st[lay][c][m] = cn;
      h_tmp[lay][c][m] = o * tanhf_(cn);
    }
  };
  auto publish = [&](int lay, unsigned short* Hpar) {
    if (tid < 32) {
      const int k4 = tid >> 4, m = (tid >> 1) & 7, seg = tid & 1;
      union { uint64_t u; _Float16 h[4]; } cv;
#pragma unroll
      for (int z = 0; z < 4; ++z)
        cv.h[z] = (_Float16)h_tmp[lay][8 * k4 + 4 * seg + z][m];
      stg64((uint64_t*)Hpar + ((size_t)(2 * sl + k4) * 16 + m) * 2 + seg, cv.u);
    }
  };

  // ================= init =================
  loadW(wlds0, p.eWhh0);
  loadW(wlds2, p.eWhh1);
  loadWV(w1, p.eWih1);
  loadBias(p.ebih0, p.ebhh0, p.ebih1, p.ebhh1, p.eWih0);
  if (tid < 64) {                 // fcW broadcast B-frag (same sigma)
    const int ks = tid >> 2, l4 = tid & 3;
    half8v h;
#pragma unroll
    for (int e = 0; e < 8; ++e) h[e] = (_Float16)p.fcW[32 * ks + 8 * l4 + e];
    fcw_c[ks][l4] = h;
  }
  if (tid == 0) { fcb_s = p.fcb[0]; done_s = 0; }
  for (int i = tid; i < 2 * 16 * 9; i += NTHR) {
    (&c_st[0][0][0])[i] = 0.f;
    (&h_tmp[0][0][0])[i] = 0.f;
  }
  // h0(-1)=0 (H0p[1]) and h1(-1)=0 (H1p[0]) come from the launch memset.

  // ================= encoder: L0(t) || L1(t-1), 1 barrier/phase =================
  for (int t = 0; t <= SEQ; ++t) {
    const int ri = (t + 1) & 1, wi = t & 1;
    const bool d0 = (t < SEQ), d1 = (t > 0);
    if (tid < 8 && d0) x_s[tid] = p.x[(size_t)(8 * g + tid) * SEQ + t];
    half8v A[16];
    f32x4 a0 = {0.f, 0.f, 0.f, 0.f}, a1 = {0.f, 0.f, 0.f, 0.f};
    ldA(H0p[ri], A);                  // h0(t-1)
    if (d0) mmL(a0, A, wlds0);        // Whh0 . h0(t-1)
    if (d1) mmV(a1, A, w1);           // Wih1 . h0(t-1)
    if (d1) { ldA(H1p[ri], A); mmL(a1, A, wlds2); }  // + Whh1 . h1(t-2)
    if (d0) gwrite(0, a0);
    if (d1) gwrite(1, a1);
    __syncthreads();
    cellsEnc(d0, d1);
    __syncthreads();
    if (d0) publish(0, H0p[wi]);
    if (d1) publish(1, H1p[wi]);
    gbar();
  }
  // leaves: h0_enc(2047) in H0p[1], h1_enc(2047) in H1p[0]

  // ================= enc -> dec transition =================
  loadW(wlds0, p.dWhh0);
  loadW(wlds2, p.dWhh1);
  loadWV(w1, p.dWih1);
  loadBias(p.dbih0, p.dbhh0, p.dbih1, p.dbhh1, p.dWih0);
  __syncthreads();
  f32x4 accPre0 = {0.f, 0.f, 0.f, 0.f};
  {
    half8v A[16];
    ldA(H0p[1], A);                   // h0_enc
    mmL(accPre0, A, wlds0);           // dWhh0 . h0_enc
  }

  // ============ decoder: A(t)=fc+Whh1+cell0, B(t)=Wih1+cell1 [+Whh0 in wait] ====
  f32x4 aP1 = {0.f, 0.f, 0.f, 0.f};
  for (int t = 0; t < SEQ; ++t) {
    { // ---- A(t): reads h1(t-1) in H1p[t&1] ----
      half8v A[16];
      ldA(H1p[t & 1], A);
      f32x4 a = {0.f, 0.f, 0.f, 0.f};
      mmL(a, A, wlds2);               // Whh1 . h1(t-1)
      aP1 = a;
      if (wv == 0) {                  // y(t-1) = fc(h1(t-1))
        f32x4 afc = {0.f, 0.f, 0.f, 0.f};
        mmFC(afc, A);
        if (nn == 0 && lo4 < 2) {
#pragma unroll
          for (int j = 0; j < 4; ++j)
            y_s[4 * lo4 + j] = (t == 0) ? 0.f : (afc[j] + fcb_s);
        }
      }
      gwrite(0, accPre0);             // Whh0 . h0(t-1) from previous B
      __syncthreads();
      cellOne(0, y_s);                // h0(t)
      if (t > 0 && sl == 0 && tid < 8)
        p.out[(size_t)(8 * g + tid) * SEQ + (t - 1)] = y_s[tid];
      __syncthreads();
      publish(0, H0p[t & 1]);
      gbar();
    }
    { // ---- B(t): reads h0(t) in H0p[t&1] ----
      half8v A[16];
      ldA(H0p[t & 1], A);
      mmV(aP1, A, w1);                // + Wih1 . h0(t)
      gwrite(1, aP1);
      __syncthreads();
      cellOne(1, nullptr);            // h1(t)
      __syncthreads();
      publish(1, H1p[(t + 1) & 1]);
      arrive();
      f32x4 a0n = {0.f, 0.f, 0.f, 0.f};
      mmL(a0n, A, wlds0);             // Whh0 . h0(t) — overlaps the wait
      wait();
      accPre0 = a0n;
    }
  }

  // ================= epilogue: y(2047) = fc(h1(2047)) in H1p[0] =================
  if (sl == 0) {
    half8v A[16];
    ldA(H1p[0], A);
    if (wv == 0) {
      f32x4 afc = {0.f, 0.f, 0.f, 0.f};
      mmFC(afc, A);
      if (nn == 0 && lo4 < 2) {
#pragma unroll
        for (int j = 0; j < 4; ++j) y_s[4 * lo4 + j] = afc[j] + fcb_s;
      }
    }
    __syncthreads();
    if (tid < 8) p.out[(size_t)(8 * g + tid) * SEQ + (SEQ - 1)] = y_s[tid];
  }
}

extern "C" void kernel_launch(void* const* d_in, const int* in_sizes, int n_in,
                              void* d_out, int out_size, void* d_ws, size_t ws_size,
                              hipStream_t stream) {
  (void)in_sizes; (void)n_in; (void)out_size; (void)ws_size;
  P p;
  p.x     = (const float*)d_in[0];
  p.eWih0 = (const float*)d_in[1];  p.eWhh0 = (const float*)d_in[2];
  p.ebih0 = (const float*)d_in[3];  p.ebhh0 = (const float*)d_in[4];
  p.eWih1 = (const float*)d_in[5];  p.eWhh1 = (const float*)d_in[6];
  p.ebih1 = (const float*)d_in[7];  p.ebhh1 = (const float*)d_in[8];
  p.dWih0 = (const float*)d_in[9];  p.dWhh0 = (const float*)d_in[10];
  p.dbih0 = (const float*)d_in[11]; p.dbhh0 = (const float*)d_in[12];
  p.dWih1 = (const float*)d_in[13]; p.dWhh1 = (const float*)d_in[14];
  p.dbih1 = (const float*)d_in[15]; p.dbhh1 = (const float*)d_in[16];
  p.fcW   = (const float*)d_in[17]; p.fcb   = (const float*)d_in[18];
  p.out   = (float*)d_out;

  p.H   = (unsigned short*)d_ws;                 // 8 groups x 64 KB = 512 KB
  p.cnt = (unsigned*)((char*)d_ws + 524288);     // 64 x 128 B counter lines

  // Zero H (h(-1)=0 + zero pad rows m>=8) and counters every launch
  // (graph-capturable, replay-safe).
  hipMemsetAsync(d_ws, 0, 524288 + 8192, stream);

  lstm_persist<<<dim3(NWG), dim3(NTHR), 0, stream>>>(p);
}

// Round 11
// 25360.280 us; speedup vs baseline: 1.2920x; 1.0858x over previous
//
#include <hip/hip_runtime.h>
#include <stdint.h>

// LSTM seq2seq (B=64, S=2048, H=512, L=2), v11 = v10 (passed, 27.5ms) with two
// latency cuts on the phase critical path:
//  * barrier arrive = per-WG packed FLAG STORE (v2-proven semantics), killing
//    v6-v10's fetch_add RMW round trip + same-line RMW serialization.
//    Poll: wave0 lanes 0-15 read 8B pairs (one load/iter), equality vs epoch,
//    2-slot parity (replay-safe); LDS release; waves1-3 VALU-burn (DVFS).
//  * encoder issues BOTH A-frag blocks (H0,H1) before any MFMA (v7 behavior):
//    one exposed LLC RTT instead of two on 2049 phases.
// Topology/transport/math identical to v10: 8 groups x 32 WGs, 16KB private H
// per matrix (M=8 pad 16), agent-scope relaxed atomics, Whh0+Whh1 in LDS,
// Wih1 in VGPRs, fc as broadcast-B MFMA, fp32 cell state in LDS.

#define NWG   256
#define NTHR  256
#define SEQ   2048
#define NH    512

typedef _Float16 half8v __attribute__((ext_vector_type(8)));
typedef float    f32x4  __attribute__((ext_vector_type(4)));

struct P {
  const float *x;
  const float *eWih0, *eWhh0, *ebih0, *ebhh0;
  const float *eWih1, *eWhh1, *ebih1, *ebhh1;
  const float *dWih0, *dWhh0, *dbih0, *dbhh0;
  const float *dWih1, *dWhh1, *dbih1, *dbhh1;
  const float *fcW, *fcb;
  float *out;
  unsigned short *H;   // 8 groups x {H0[2],H1[2]} x [64 ks4][16 m][8 e] fp16
  unsigned *flg;       // 8 groups x 2 slots x 64 dwords (256B stride), zeroed/launch
};

__device__ __forceinline__ uint64_t ldg64(const uint64_t* p) {
  return __hip_atomic_load(p, __ATOMIC_RELAXED, __HIP_MEMORY_SCOPE_AGENT);
}
__device__ __forceinline__ void stg64(uint64_t* p, uint64_t v) {
  __hip_atomic_store(p, v, __ATOMIC_RELAXED, __HIP_MEMORY_SCOPE_AGENT);
}
__device__ __forceinline__ float sigf(float v)   { return 1.f / (1.f + __expf(-v)); }
__device__ __forceinline__ float tanhf_(float v) { return 2.f * sigf(2.f * v) - 1.f; }

__global__ __launch_bounds__(NTHR, 1) void lstm_persist(P p) {
  __shared__ half8v wlds0[4][16][64];  // 64KB Whh0 slice [q][ks][lane]
  __shared__ half8v wlds2[4][16][64];  // 64KB Whh1 slice [q][ks][lane]
  __shared__ half8v fcw_c[16][4];      // fcW broadcast B-frags
  __shared__ float  gate_s[2][4][8][17]; // [lay][q][m][c] padded
  __shared__ float  bias_s[2][4][16];  // current-stage bih+bhh [lay][q][c]
  __shared__ float  w0_s[4][16];       // current-stage Wih0 col [q][c]
  __shared__ float  c_st[2][16][9];    // fp32 cell state [lay][c][m]
  __shared__ float  h_tmp[2][16][9];   // fp32 h' staging  [lay][c][m]
  __shared__ float  x_s[8], y_s[8];
  __shared__ float  fcb_s;
  __shared__ unsigned done_s;

  const int wg   = blockIdx.x;
  const int g    = wg & 7;        // batch group: samples [8g, 8g+8)
  const int sl   = wg >> 3;       // hidden slice 0..31: cols [16sl, 16sl+16)
  const int tid  = threadIdx.x;
  const int lane = tid & 63;
  const int wv   = tid >> 6;      // wave = gate q (i,f,g,o)
  const int lo4  = lane >> 4;
  const int nn   = lane & 15;

  unsigned short* Hg = p.H + (size_t)g * 32768;
  unsigned short* H0p[2] = {Hg, Hg + 8192};
  unsigned short* H1p[2] = {Hg + 16384, Hg + 24576};
  unsigned epoch = 0;

  half8v w1[16];                  // Wih1 own-gate-rows B-frags (64 VGPR)

  // ---- private group barrier: packed flag stores + 16-lane pair poll ----
  auto arrive = [&]() {
    epoch++;
    __syncthreads();              // drains vmcnt(0): publishes complete at LLC
    if (tid == 0)
      __hip_atomic_store(p.flg + (g * 2 + (epoch & 1)) * 64 + sl, epoch,
                         __ATOMIC_RELAXED, __HIP_MEMORY_SCOPE_AGENT);
  };
  auto wait = [&]() {
    if (wv == 0) {
      if (lane < 16) {            // 2 flags per lane, one 8B load per iter
        const uint64_t tgt = (uint64_t)epoch * 0x100000001ull;
        const uint64_t* fp =
            (const uint64_t*)(p.flg + (g * 2 + (epoch & 1)) * 64) + lane;
        while (__hip_atomic_load(fp, __ATOMIC_RELAXED,
                                 __HIP_MEMORY_SCOPE_AGENT) != tgt) {}
      }
      // wave reconverges here: all 32 flags confirmed
      if (lane == 0)
        __hip_atomic_store(&done_s, epoch, __ATOMIC_RELEASE,
                           __HIP_MEMORY_SCOPE_WORKGROUP);
    } else {
      unsigned dummy = tid;
      while (__hip_atomic_load(&done_s, __ATOMIC_ACQUIRE,
                               __HIP_MEMORY_SCOPE_WORKGROUP) != epoch) {
#pragma unroll
        for (int i = 0; i < 32; ++i)
          asm volatile("v_add_u32 %0, %0, 1" : "+v"(dummy));   // keep SIMD busy
      }
      asm volatile("" :: "v"(dummy));
    }
    __builtin_amdgcn_fence(__ATOMIC_ACQUIRE, "workgroup");
    __syncthreads();
  };
  auto gbar = [&]() { arrive(); wait(); };

  // ---- weight gathers (sigma: k = 32ks + 8*lo4 + e on BOTH A and B sides) ----
  auto loadW = [&](half8v (*wl)[16][64], const float* __restrict__ W) {
    for (int idx = tid; idx < 4096; idx += NTHR) {
      const int q = idx >> 10, ks = (idx >> 6) & 15, l = idx & 63;
      const int gr = 512 * q + 16 * sl + (l & 15);
      const float* base = W + (size_t)gr * NH + 32 * ks + 8 * (l >> 4);
      f32x4 wa, wb;
      __builtin_memcpy(&wa, base, 16);
      __builtin_memcpy(&wb, base + 4, 16);
      half8v h;
      h[0]=(_Float16)wa[0]; h[1]=(_Float16)wa[1]; h[2]=(_Float16)wa[2]; h[3]=(_Float16)wa[3];
      h[4]=(_Float16)wb[0]; h[5]=(_Float16)wb[1]; h[6]=(_Float16)wb[2]; h[7]=(_Float16)wb[3];
      wl[q][ks][l] = h;
    }
  };
  auto loadWV = [&](half8v* w, const float* __restrict__ W) {
    const int gr = 512 * wv + 16 * sl + nn;
    const float* base = W + (size_t)gr * NH + 8 * lo4;
#pragma unroll
    for (int ks = 0; ks < 16; ++ks) {
      f32x4 wa, wb;
      __builtin_memcpy(&wa, base + 32 * ks, 16);
      __builtin_memcpy(&wb, base + 32 * ks + 4, 16);
      half8v h;
      h[0]=(_Float16)wa[0]; h[1]=(_Float16)wa[1]; h[2]=(_Float16)wa[2]; h[3]=(_Float16)wa[3];
      h[4]=(_Float16)wb[0]; h[5]=(_Float16)wb[1]; h[6]=(_Float16)wb[2]; h[7]=(_Float16)wb[3];
      w[ks] = h;
    }
  };
  auto loadBias = [&](const float* bi0, const float* bh0, const float* bi1,
                      const float* bh1, const float* Wi0) {
    if (tid < 128) {
      const int lay = tid >> 6, q = (tid >> 4) & 3, c = tid & 15;
      const int gr = 512 * q + 16 * sl + c;
      bias_s[lay][q][c] = lay ? (bi1[gr] + bh1[gr]) : (bi0[gr] + bh0[gr]);
    }
    if (tid < 64) {
      const int q = tid >> 4, c = tid & 15;
      w0_s[q][c] = Wi0[512 * q + 16 * sl + c];
    }
  };

  // ---- A-frags: [64 ks4][16 m][8 e]; rows m>=8 stay memset-zero ----
  auto ldA = [&](const unsigned short* Hm, half8v* A) {
    const uint64_t* bp = (const uint64_t*)Hm + (size_t)(lane & 15) * 2;
#pragma unroll
    for (int ks = 0; ks < 16; ++ks) {
      const int i = (4 * ks + lo4) * 32;
      union { uint64_t u[2]; half8v h; } T;
      T.u[0] = ldg64(bp + i);
      T.u[1] = ldg64(bp + i + 1);
      A[ks] = T.h;
    }
  };

  auto mmL = [&](f32x4& a, const half8v* A, half8v (*wl)[16][64]) {
#pragma unroll
    for (int ks = 0; ks < 16; ++ks)
      a = __builtin_amdgcn_mfma_f32_16x16x32_f16(A[ks], wl[wv][ks][lane], a, 0, 0, 0);
  };
  auto mmV = [&](f32x4& a, const half8v* A, const half8v* w) {
#pragma unroll
    for (int ks = 0; ks < 16; ++ks)
      a = __builtin_amdgcn_mfma_f32_16x16x32_f16(A[ks], w[ks], a, 0, 0, 0);
  };
  auto mmFC = [&](f32x4& a, const half8v* A) {
#pragma unroll
    for (int ks = 0; ks < 16; ++ks)
      a = __builtin_amdgcn_mfma_f32_16x16x32_f16(A[ks], fcw_c[ks][lo4], a, 0, 0, 0);
  };

  auto gwrite = [&](int lay, const f32x4& acc) {
    if (lo4 < 2) {
#pragma unroll
      for (int j = 0; j < 4; ++j) gate_s[lay][wv][4 * lo4 + j][nn] = acc[j];
    }
  };
  auto cellOne = [&](int lay, const float* inp8) {
    if (tid < 128) {
      const int c = tid & 15, m = tid >> 4;
      float g0 = gate_s[lay][0][m][c] + bias_s[lay][0][c];
      float g1 = gate_s[lay][1][m][c] + bias_s[lay][1][c];
      float g2 = gate_s[lay][2][m][c] + bias_s[lay][2][c];
      float g3 = gate_s[lay][3][m][c] + bias_s[lay][3][c];
      if (lay == 0) {
        const float xm = inp8[m];
        g0 += xm * w0_s[0][c]; g1 += xm * w0_s[1][c];
        g2 += xm * w0_s[2][c]; g3 += xm * w0_s[3][c];
      }
      const float i = sigf(g0), f = sigf(g1), gg = tanhf_(g2), o = sigf(g3);
      const float cn = f * c_st[lay][c][m] + i * gg;
      c_st[lay][c][m] = cn;
      h_tmp[lay][c][m] = o * tanhf_(cn);
    }
  };
  auto cellsEnc = [&](bool d0, bool d1) {
    const int lay = tid >> 7, u = tid & 127, c = u & 15, m = u >> 4;
    if (lay ? d1 : d0) {
      float g0 = gate_s[lay][0][m][c] + bias_s[lay][0][c];
      float g1 = gate_s[lay][1][m][c] + bias_s[lay][1][c];
      float g2 = gate_s[lay][2][m][c] + bias_s[lay][2][c];
      float g3 = gate_s[lay][3][m][c] + bias_s[lay][3][c];
      if (lay == 0) {
        const float xm = x_s[m];
        g0 += xm * w0_s[0][c]; g1 += xm * w0_s[1][c];
        g2 += xm * w0_s[2][c]; g3 += xm * w0_s[3][c];
      }
      const float i = sigf(g0), f = sigf(g1), gg = tanhf_(g2), o = sigf(g3);
      const float cn = f * c_st[lay][c][m] + i * gg;
      c_st[lay][c][m] = cn;
      h_tmp[lay][c][m] = o * tanhf_(cn);
    }
  };
  auto publish = [&](int lay, unsigned short* Hpar) {
    if (tid < 32) {
      const int k4 = tid >> 4, m = (tid >> 1) & 7, seg = tid & 1;
      union { uint64_t u; _Float16 h[4]; } cv;
#pragma unroll
      for (int z = 0; z < 4; ++z)
        cv.h[z] = (_Float16)h_tmp[lay][8 * k4 + 4 * seg + z][m];
      stg64((uint64_t*)Hpar + ((size_t)(2 * sl + k4) * 16 + m) * 2 + seg, cv.u);
    }
  };

  // ================= init =================
  loadW(wlds0, p.eWhh0);
  loadW(wlds2, p.eWhh1);
  loadWV(w1, p.eWih1);
  loadBias(p.ebih0, p.ebhh0, p.ebih1, p.ebhh1, p.eWih0);
  if (tid < 64) {                 // fcW broadcast B-frag (same sigma)
    const int ks = tid >> 2, l4 = tid & 3;
    half8v h;
#pragma unroll
    for (int e = 0; e < 8; ++e) h[e] = (_Float16)p.fcW[32 * ks + 8 * l4 + e];
    fcw_c[ks][l4] = h;
  }
  if (tid == 0) { fcb_s = p.fcb[0]; done_s = 0; }
  for (int i = tid; i < 2 * 16 * 9; i += NTHR) {
    (&c_st[0][0][0])[i] = 0.f;
    (&h_tmp[0][0][0])[i] = 0.f;
  }
  // h0(-1)=0 (H0p[1]) and h1(-1)=0 (H1p[0]) come from the launch memset.

  // ================= encoder: L0(t) || L1(t-1), 1 barrier/phase =================
  for (int t = 0; t <= SEQ; ++t) {
    const int ri = (t + 1) & 1, wi = t & 1;
    const bool d0 = (t < SEQ), d1 = (t > 0);
    if (tid < 8 && d0) x_s[tid] = p.x[(size_t)(8 * g + tid) * SEQ + t];
    half8v A0[16], A1[16];
    ldA(H0p[ri], A0);                 // h0(t-1)  — both blocks issued up-front
    if (d1) ldA(H1p[ri], A1);         // h1(t-2)
    f32x4 a0 = {0.f, 0.f, 0.f, 0.f}, a1 = {0.f, 0.f, 0.f, 0.f};
    if (d0) mmL(a0, A0, wlds0);       // Whh0 . h0(t-1)
    if (d1) mmV(a1, A0, w1);          // Wih1 . h0(t-1)
    if (d1) mmL(a1, A1, wlds2);       // + Whh1 . h1(t-2)
    if (d0) gwrite(0, a0);
    if (d1) gwrite(1, a1);
    __syncthreads();
    cellsEnc(d0, d1);
    __syncthreads();
    if (d0) publish(0, H0p[wi]);
    if (d1) publish(1, H1p[wi]);
    gbar();
  }
  // leaves: h0_enc(2047) in H0p[1], h1_enc(2047) in H1p[0]

  // ================= enc -> dec transition =================
  loadW(wlds0, p.dWhh0);
  loadW(wlds2, p.dWhh1);
  loadWV(w1, p.dWih1);
  loadBias(p.dbih0, p.dbhh0, p.dbih1, p.dbhh1, p.dWih0);
  __syncthreads();
  f32x4 accPre0 = {0.f, 0.f, 0.f, 0.f};
  {
    half8v A[16];
    ldA(H0p[1], A);                   // h0_enc
    mmL(accPre0, A, wlds0);           // dWhh0 . h0_enc
  }

  // ============ decoder: A(t)=fc+Whh1+cell0, B(t)=Wih1+cell1 [+Whh0 in wait] ====
  f32x4 aP1 = {0.f, 0.f, 0.f, 0.f};
  for (int t = 0; t < SEQ; ++t) {
    { // ---- A(t): reads h1(t-1) in H1p[t&1] ----
      half8v A[16];
      ldA(H1p[t & 1], A);
      f32x4 a = {0.f, 0.f, 0.f, 0.f};
      mmL(a, A, wlds2);               // Whh1 . h1(t-1)
      aP1 = a;
      if (wv == 0) {                  // y(t-1) = fc(h1(t-1))
        f32x4 afc = {0.f, 0.f, 0.f, 0.f};
        mmFC(afc, A);
        if (nn == 0 && lo4 < 2) {
#pragma unroll
          for (int j = 0; j < 4; ++j)
            y_s[4 * lo4 + j] = (t == 0) ? 0.f : (afc[j] + fcb_s);
        }
      }
      gwrite(0, accPre0);             // Whh0 . h0(t-1) from previous B
      __syncthreads();
      cellOne(0, y_s);                // h0(t)
      if (t > 0 && sl == 0 && tid < 8)
        p.out[(size_t)(8 * g + tid) * SEQ + (t - 1)] = y_s[tid];
      __syncthreads();
      publish(0, H0p[t & 1]);
      gbar();
    }
    { // ---- B(t): reads h0(t) in H0p[t&1] ----
      half8v A[16];
      ldA(H0p[t & 1], A);
      mmV(aP1, A, w1);                // + Wih1 . h0(t)
      gwrite(1, aP1);
      __syncthreads();
      cellOne(1, nullptr);            // h1(t)
      __syncthreads();
      publish(1, H1p[(t + 1) & 1]);
      arrive();
      f32x4 a0n = {0.f, 0.f, 0.f, 0.f};
      mmL(a0n, A, wlds0);             // Whh0 . h0(t) — overlaps the wait
      wait();
      accPre0 = a0n;
    }
  }

  // ================= epilogue: y(2047) = fc(h1(2047)) in H1p[0] =================
  if (sl == 0) {
    half8v A[16];
    ldA(H1p[0], A);
    if (wv == 0) {
      f32x4 afc = {0.f, 0.f, 0.f, 0.f};
      mmFC(afc, A);
      if (nn == 0 && lo4 < 2) {
#pragma unroll
        for (int j = 0; j < 4; ++j) y_s[4 * lo4 + j] = afc[j] + fcb_s;
      }
    }
    __syncthreads();
    if (tid < 8) p.out[(size_t)(8 * g + tid) * SEQ + (SEQ - 1)] = y_s[tid];
  }
}

extern "C" void kernel_launch(void* const* d_in, const int* in_sizes, int n_in,
                              void* d_out, int out_size, void* d_ws, size_t ws_size,
                              hipStream_t stream) {
  (void)in_sizes; (void)n_in; (void)out_size; (void)ws_size;
  P p;
  p.x     = (const float*)d_in[0];
  p.eWih0 = (const float*)d_in[1];  p.eWhh0 = (const float*)d_in[2];
  p.ebih0 = (const float*)d_in[3];  p.ebhh0 = (const float*)d_in[4];
  p.eWih1 = (const float*)d_in[5];  p.eWhh1 = (const float*)d_in[6];
  p.ebih1 = (const float*)d_in[7];  p.ebhh1 = (const float*)d_in[8];
  p.dWih0 = (const float*)d_in[9];  p.dWhh0 = (const float*)d_in[10];
  p.dbih0 = (const float*)d_in[11]; p.dbhh0 = (const float*)d_in[12];
  p.dWih1 = (const float*)d_in[13]; p.dWhh1 = (const float*)d_in[14];
  p.dbih1 = (const float*)d_in[15]; p.dbhh1 = (const float*)d_in[16];
  p.fcW   = (const float*)d_in[17]; p.fcb   = (const float*)d_in[18];
  p.out   = (float*)d_out;

  p.H   = (unsigned short*)d_ws;                 // 8 groups x 64 KB = 512 KB
  p.flg = (unsigned*)((char*)d_ws + 524288);     // 8 x 2 x 256 B flag blocks

  // Zero H (h(-1)=0 + zero pad rows m>=8) and flags every launch
  // (graph-capturable, replay-safe).
  hipMemsetAsync(d_ws, 0, 524288 + 4096, stream);

  lstm_persist<<<dim3(NWG), dim3(NTHR), 0, stream>>>(p);
}

// Round 12
// 25282.066 us; speedup vs baseline: 1.2960x; 1.0031x over previous
//
#include <hip/hip_runtime.h>
#include <stdint.h>

// LSTM seq2seq (B=64, S=2048, H=512, L=2), v12 = v11 (passed, 25.4ms) + DVFS
// attack:
//  * dense burn while waiting: 4 independent FMA chains, 64 FMAs per LDS
//    check, on waves 1-3 (~80% issue duty). v10's weak burn (1 dep chain,
//    check/32 adds) left VALUBusy at 10% -> governor parked the clock
//    (25<->66ms dispatch swings on identical work = DVFS signature; cycle
//    model says phase should be ~1.2us @2.4GHz, measured 4.1us).
//  * decoder-A p.out HBM store moved into the wait window (after arrive):
//    it was inside the pre-flag vmcnt(0) drain -> group leader's flag was
//    ~900cy late every phase; whole group waited on it.
// Everything else bit-identical to v11: 8 groups x 32 WGs, packed flag-store
// barrier + 16-lane pair poll, agent-scope relaxed atomic transport, sigma
// k-perm layout, Whh0+Whh1 LDS / Wih1 VGPR, fc-as-broadcast-MFMA.

#define NWG   256
#define NTHR  256
#define SEQ   2048
#define NH    512

typedef _Float16 half8v __attribute__((ext_vector_type(8)));
typedef float    f32x4  __attribute__((ext_vector_type(4)));

struct P {
  const float *x;
  const float *eWih0, *eWhh0, *ebih0, *ebhh0;
  const float *eWih1, *eWhh1, *ebih1, *ebhh1;
  const float *dWih0, *dWhh0, *dbih0, *dbhh0;
  const float *dWih1, *dWhh1, *dbih1, *dbhh1;
  const float *fcW, *fcb;
  float *out;
  unsigned short *H;   // 8 groups x {H0[2],H1[2]} x [64 ks4][16 m][8 e] fp16
  unsigned *flg;       // 8 groups x 2 slots x 64 dwords (256B stride), zeroed/launch
};

__device__ __forceinline__ uint64_t ldg64(const uint64_t* p) {
  return __hip_atomic_load(p, __ATOMIC_RELAXED, __HIP_MEMORY_SCOPE_AGENT);
}
__device__ __forceinline__ void stg64(uint64_t* p, uint64_t v) {
  __hip_atomic_store(p, v, __ATOMIC_RELAXED, __HIP_MEMORY_SCOPE_AGENT);
}
__device__ __forceinline__ float sigf(float v)   { return 1.f / (1.f + __expf(-v)); }
__device__ __forceinline__ float tanhf_(float v) { return 2.f * sigf(2.f * v) - 1.f; }

__global__ __launch_bounds__(NTHR, 1) void lstm_persist(P p) {
  __shared__ half8v wlds0[4][16][64];  // 64KB Whh0 slice [q][ks][lane]
  __shared__ half8v wlds2[4][16][64];  // 64KB Whh1 slice [q][ks][lane]
  __shared__ half8v fcw_c[16][4];      // fcW broadcast B-frags
  __shared__ float  gate_s[2][4][8][17]; // [lay][q][m][c] padded
  __shared__ float  bias_s[2][4][16];  // current-stage bih+bhh [lay][q][c]
  __shared__ float  w0_s[4][16];       // current-stage Wih0 col [q][c]
  __shared__ float  c_st[2][16][9];    // fp32 cell state [lay][c][m]
  __shared__ float  h_tmp[2][16][9];   // fp32 h' staging  [lay][c][m]
  __shared__ float  x_s[8], y_s[8];
  __shared__ float  fcb_s;
  __shared__ unsigned done_s;

  const int wg   = blockIdx.x;
  const int g    = wg & 7;        // batch group: samples [8g, 8g+8)
  const int sl   = wg >> 3;       // hidden slice 0..31: cols [16sl, 16sl+16)
  const int tid  = threadIdx.x;
  const int lane = tid & 63;
  const int wv   = tid >> 6;      // wave = gate q (i,f,g,o)
  const int lo4  = lane >> 4;
  const int nn   = lane & 15;

  unsigned short* Hg = p.H + (size_t)g * 32768;
  unsigned short* H0p[2] = {Hg, Hg + 8192};
  unsigned short* H1p[2] = {Hg + 16384, Hg + 24576};
  unsigned epoch = 0;

  half8v w1[16];                  // Wih1 own-gate-rows B-frags (64 VGPR)

  // ---- private group barrier: packed flag stores + 16-lane pair poll ----
  auto arrive = [&]() {
    epoch++;
    __syncthreads();              // drains vmcnt(0): publishes complete at LLC
    if (tid == 0)
      __hip_atomic_store(p.flg + (g * 2 + (epoch & 1)) * 64 + sl, epoch,
                         __ATOMIC_RELAXED, __HIP_MEMORY_SCOPE_AGENT);
  };
  auto wait = [&]() {
    if (wv == 0) {
      if (lane < 16) {            // 2 flags per lane, one 8B load per iter
        const uint64_t tgt = (uint64_t)epoch * 0x100000001ull;
        const uint64_t* fp =
            (const uint64_t*)(p.flg + (g * 2 + (epoch & 1)) * 64) + lane;
        while (__hip_atomic_load(fp, __ATOMIC_RELAXED,
                                 __HIP_MEMORY_SCOPE_AGENT) != tgt) {}
      }
      // wave reconverges here: all 32 flags confirmed
      if (lane == 0)
        __hip_atomic_store(&done_s, epoch, __ATOMIC_RELEASE,
                           __HIP_MEMORY_SCOPE_WORKGROUP);
    } else {
      // dense DVFS burn: 4 independent FMA chains, check flag every 64 FMAs
      float b0 = (float)tid, b1 = b0 + 1.f, b2 = b0 + 2.f, b3 = b0 + 3.f;
      while (__hip_atomic_load(&done_s, __ATOMIC_ACQUIRE,
                               __HIP_MEMORY_SCOPE_WORKGROUP) != epoch) {
#pragma unroll
        for (int i = 0; i < 16; ++i) {
          b0 = __builtin_fmaf(b0, 1.0000001f, 1.0e-7f);
          b1 = __builtin_fmaf(b1, 1.0000001f, 2.0e-7f);
          b2 = __builtin_fmaf(b2, 1.0000001f, 3.0e-7f);
          b3 = __builtin_fmaf(b3, 1.0000001f, 4.0e-7f);
        }
      }
      asm volatile("" :: "v"(b0), "v"(b1), "v"(b2), "v"(b3));
    }
    __builtin_amdgcn_fence(__ATOMIC_ACQUIRE, "workgroup");
    __syncthreads();
  };
  auto gbar = [&]() { arrive(); wait(); };

  // ---- weight gathers (sigma: k = 32ks + 8*lo4 + e on BOTH A and B sides) ----
  auto loadW = [&](half8v (*wl)[16][64], const float* __restrict__ W) {
    for (int idx = tid; idx < 4096; idx += NTHR) {
      const int q = idx >> 10, ks = (idx >> 6) & 15, l = idx & 63;
      const int gr = 512 * q + 16 * sl + (l & 15);
      const float* base = W + (size_t)gr * NH + 32 * ks + 8 * (l >> 4);
      f32x4 wa, wb;
      __builtin_memcpy(&wa, base, 16);
      __builtin_memcpy(&wb, base + 4, 16);
      half8v h;
      h[0]=(_Float16)wa[0]; h[1]=(_Float16)wa[1]; h[2]=(_Float16)wa[2]; h[3]=(_Float16)wa[3];
      h[4]=(_Float16)wb[0]; h[5]=(_Float16)wb[1]; h[6]=(_Float16)wb[2]; h[7]=(_Float16)wb[3];
      wl[q][ks][l] = h;
    }
  };
  auto loadWV = [&](half8v* w, const float* __restrict__ W) {
    const int gr = 512 * wv + 16 * sl + nn;
    const float* base = W + (size_t)gr * NH + 8 * lo4;
#pragma unroll
    for (int ks = 0; ks < 16; ++ks) {
      f32x4 wa, wb;
      __builtin_memcpy(&wa, base + 32 * ks, 16);
      __builtin_memcpy(&wb, base + 32 * ks + 4, 16);
      half8v h;
      h[0]=(_Float16)wa[0]; h[1]=(_Float16)wa[1]; h[2]=(_Float16)wa[2]; h[3]=(_Float16)wa[3];
      h[4]=(_Float16)wb[0]; h[5]=(_Float16)wb[1]; h[6]=(_Float16)wb[2]; h[7]=(_Float16)wb[3];
      w[ks] = h;
    }
  };
  auto loadBias = [&](const float* bi0, const float* bh0, const float* bi1,
                      const float* bh1, const float* Wi0) {
    if (tid < 128) {
      const int lay = tid >> 6, q = (tid >> 4) & 3, c = tid & 15;
      const int gr = 512 * q + 16 * sl + c;
      bias_s[lay][q][c] = lay ? (bi1[gr] + bh1[gr]) : (bi0[gr] + bh0[gr]);
    }
    if (tid < 64) {
      const int q = tid >> 4, c = tid & 15;
      w0_s[q][c] = Wi0[512 * q + 16 * sl + c];
    }
  };

  // ---- A-frags: [64 ks4][16 m][8 e]; rows m>=8 stay memset-zero ----
  auto ldA = [&](const unsigned short* Hm, half8v* A) {
    const uint64_t* bp = (const uint64_t*)Hm + (size_t)(lane & 15) * 2;
#pragma unroll
    for (int ks = 0; ks < 16; ++ks) {
      const int i = (4 * ks + lo4) * 32;
      union { uint64_t u[2]; half8v h; } T;
      T.u[0] = ldg64(bp + i);
      T.u[1] = ldg64(bp + i + 1);
      A[ks] = T.h;
    }
  };

  auto mmL = [&](f32x4& a, const half8v* A, half8v (*wl)[16][64]) {
#pragma unroll
    for (int ks = 0; ks < 16; ++ks)
      a = __builtin_amdgcn_mfma_f32_16x16x32_f16(A[ks], wl[wv][ks][lane], a, 0, 0, 0);
  };
  auto mmV = [&](f32x4& a, const half8v* A, const half8v* w) {
#pragma unroll
    for (int ks = 0; ks < 16; ++ks)
      a = __builtin_amdgcn_mfma_f32_16x16x32_f16(A[ks], w[ks], a, 0, 0, 0);
  };
  auto mmFC = [&](f32x4& a, const half8v* A) {
#pragma unroll
    for (int ks = 0; ks < 16; ++ks)
      a = __builtin_amdgcn_mfma_f32_16x16x32_f16(A[ks], fcw_c[ks][lo4], a, 0, 0, 0);
  };

  auto gwrite = [&](int lay, const f32x4& acc) {
    if (lo4 < 2) {
#pragma unroll
      for (int j = 0; j < 4; ++j) gate_s[lay][wv][4 * lo4 + j][nn] = acc[j];
    }
  };
  auto cellOne = [&](int lay, const float* inp8) {
    if (tid < 128) {
      const int c = tid & 15, m = tid >> 4;
      float g0 = gate_s[lay][0][m][c] + bias_s[lay][0][c];
      float g1 = gate_s[lay][1][m][c] + bias_s[lay][1][c];
      float g2 = gate_s[lay][2][m][c] + bias_s[lay][2][c];
      float g3 = gate_s[lay][3][m][c] + bias_s[lay][3][c];
      if (lay == 0) {
        const float xm = inp8[m];
        g0 += xm * w0_s[0][c]; g1 += xm * w0_s[1][c];
        g2 += xm * w0_s[2][c]; g3 += xm * w0_s[3][c];
      }
      const float i = sigf(g0), f = sigf(g1), gg = tanhf_(g2), o = sigf(g3);
      const float cn = f * c_st[lay][c][m] + i * gg;
      c_st[lay][c][m] = cn;
      h_tmp[lay][c][m] = o * tanhf_(cn);
    }
  };
  auto cellsEnc = [&](bool d0, bool d1) {
    const int lay = tid >> 7, u = tid & 127, c = u & 15, m = u >> 4;
    if (lay ? d1 : d0) {
      float g0 = gate_s[lay][0][m][c] + bias_s[lay][0][c];
      float g1 = gate_s[lay][1][m][c] + bias_s[lay][1][c];
      float g2 = gate_s[lay][2][m][c] + bias_s[lay][2][c];
      float g3 = gate_s[lay][3][m][c] + bias_s[lay][3][c];
      if (lay == 0) {
        const float xm = x_s[m];
        g0 += xm * w0_s[0][c]; g1 += xm * w0_s[1][c];
        g2 += xm * w0_s[2][c]; g3 += xm * w0_s[3][c];
      }
      const float i = sigf(g0), f = sigf(g1), gg = tanhf_(g2), o = sigf(g3);
      const float cn = f * c_st[lay][c][m] + i * gg;
      c_st[lay][c][m] = cn;
      h_tmp[lay][c][m] = o * tanhf_(cn);
    }
  };
  auto publish = [&](int lay, unsigned short* Hpar) {
    if (tid < 32) {
      const int k4 = tid >> 4, m = (tid >> 1) & 7, seg = tid & 1;
      union { uint64_t u; _Float16 h[4]; } cv;
#pragma unroll
      for (int z = 0; z < 4; ++z)
        cv.h[z] = (_Float16)h_tmp[lay][8 * k4 + 4 * seg + z][m];
      stg64((uint64_t*)Hpar + ((size_t)(2 * sl + k4) * 16 + m) * 2 + seg, cv.u);
    }
  };

  // ================= init =================
  loadW(wlds0, p.eWhh0);
  loadW(wlds2, p.eWhh1);
  loadWV(w1, p.eWih1);
  loadBias(p.ebih0, p.ebhh0, p.ebih1, p.ebhh1, p.eWih0);
  if (tid < 64) {                 // fcW broadcast B-frag (same sigma)
    const int ks = tid >> 2, l4 = tid & 3;
    half8v h;
#pragma unroll
    for (int e = 0; e < 8; ++e) h[e] = (_Float16)p.fcW[32 * ks + 8 * l4 + e];
    fcw_c[ks][l4] = h;
  }
  if (tid == 0) { fcb_s = p.fcb[0]; done_s = 0; }
  for (int i = tid; i < 2 * 16 * 9; i += NTHR) {
    (&c_st[0][0][0])[i] = 0.f;
    (&h_tmp[0][0][0])[i] = 0.f;
  }
  // h0(-1)=0 (H0p[1]) and h1(-1)=0 (H1p[0]) come from the launch memset.

  // ================= encoder: L0(t) || L1(t-1), 1 barrier/phase =================
  for (int t = 0; t <= SEQ; ++t) {
    const int ri = (t + 1) & 1, wi = t & 1;
    const bool d0 = (t < SEQ), d1 = (t > 0);
    if (tid < 8 && d0) x_s[tid] = p.x[(size_t)(8 * g + tid) * SEQ + t];
    half8v A0[16], A1[16];
    ldA(H0p[ri], A0);                 // h0(t-1)  — both blocks issued up-front
    if (d1) ldA(H1p[ri], A1);         // h1(t-2)
    f32x4 a0 = {0.f, 0.f, 0.f, 0.f}, a1 = {0.f, 0.f, 0.f, 0.f};
    if (d0) mmL(a0, A0, wlds0);       // Whh0 . h0(t-1)
    if (d1) mmV(a1, A0, w1);          // Wih1 . h0(t-1)
    if (d1) mmL(a1, A1, wlds2);       // + Whh1 . h1(t-2)
    if (d0) gwrite(0, a0);
    if (d1) gwrite(1, a1);
    __syncthreads();
    cellsEnc(d0, d1);
    __syncthreads();
    if (d0) publish(0, H0p[wi]);
    if (d1) publish(1, H1p[wi]);
    gbar();
  }
  // leaves: h0_enc(2047) in H0p[1], h1_enc(2047) in H1p[0]

  // ================= enc -> dec transition =================
  loadW(wlds0, p.dWhh0);
  loadW(wlds2, p.dWhh1);
  loadWV(w1, p.dWih1);
  loadBias(p.dbih0, p.dbhh0, p.dbih1, p.dbhh1, p.dWih0);
  __syncthreads();
  f32x4 accPre0 = {0.f, 0.f, 0.f, 0.f};
  {
    half8v A[16];
    ldA(H0p[1], A);                   // h0_enc
    mmL(accPre0, A, wlds0);           // dWhh0 . h0_enc
  }

  // ============ decoder: A(t)=fc+Whh1+cell0, B(t)=Wih1+cell1 [+Whh0 in wait] ====
  f32x4 aP1 = {0.f, 0.f, 0.f, 0.f};
  for (int t = 0; t < SEQ; ++t) {
    { // ---- A(t): reads h1(t-1) in H1p[t&1] ----
      half8v A[16];
      ldA(H1p[t & 1], A);
      f32x4 a = {0.f, 0.f, 0.f, 0.f};
      mmL(a, A, wlds2);               // Whh1 . h1(t-1)
      aP1 = a;
      if (wv == 0) {                  // y(t-1) = fc(h1(t-1))
        f32x4 afc = {0.f, 0.f, 0.f, 0.f};
        mmFC(afc, A);
        if (nn == 0 && lo4 < 2) {
#pragma unroll
          for (int j = 0; j < 4; ++j)
            y_s[4 * lo4 + j] = (t == 0) ? 0.f : (afc[j] + fcb_s);
        }
      }
      gwrite(0, accPre0);             // Whh0 . h0(t-1) from previous B
      __syncthreads();
      cellOne(0, y_s);                // h0(t)
      __syncthreads();
      publish(0, H0p[t & 1]);
      arrive();
      // y output store inside the wait window: off the pre-flag drain path
      if (t > 0 && sl == 0 && tid < 8)
        p.out[(size_t)(8 * g + tid) * SEQ + (t - 1)] = y_s[tid];
      wait();
    }
    { // ---- B(t): reads h0(t) in H0p[t&1] ----
      half8v A[16];
      ldA(H0p[t & 1], A);
      mmV(aP1, A, w1);                // + Wih1 . h0(t)
      gwrite(1, aP1);
      __syncthreads();
      cellOne(1, nullptr);            // h1(t)
      __syncthreads();
      publish(1, H1p[(t + 1) & 1]);
      arrive();
      f32x4 a0n = {0.f, 0.f, 0.f, 0.f};
      mmL(a0n, A, wlds0);             // Whh0 . h0(t) — overlaps the wait
      wait();
      accPre0 = a0n;
    }
  }

  // ================= epilogue: y(2047) = fc(h1(2047)) in H1p[0] =================
  if (sl == 0) {
    half8v A[16];
    ldA(H1p[0], A);
    if (wv == 0) {
      f32x4 afc = {0.f, 0.f, 0.f, 0.f};
      mmFC(afc, A);
      if (nn == 0 && lo4 < 2) {
#pragma unroll
        for (int j = 0; j < 4; ++j) y_s[4 * lo4 + j] = afc[j] + fcb_s;
      }
    }
    __syncthreads();
    if (tid < 8) p.out[(size_t)(8 * g + tid) * SEQ + (SEQ - 1)] = y_s[tid];
  }
}

extern "C" void kernel_launch(void* const* d_in, const int* in_sizes, int n_in,
                              void* d_out, int out_size, void* d_ws, size_t ws_size,
                              hipStream_t stream) {
  (void)in_sizes; (void)n_in; (void)out_size; (void)ws_size;
  P p;
  p.x     = (const float*)d_in[0];
  p.eWih0 = (const float*)d_in[1];  p.eWhh0 = (const float*)d_in[2];
  p.ebih0 = (const float*)d_in[3];  p.ebhh0 = (const float*)d_in[4];
  p.eWih1 = (const float*)d_in[5];  p.eWhh1 = (const float*)d_in[6];
  p.ebih1 = (const float*)d_in[7];  p.ebhh1 = (const float*)d_in[8];
  p.dWih0 = (const float*)d_in[9];  p.dWhh0 = (const float*)d_in[10];
  p.dbih0 = (const float*)d_in[11]; p.dbhh0 = (const float*)d_in[12];
  p.dWih1 = (const float*)d_in[13]; p.dWhh1 = (const float*)d_in[14];
  p.dbih1 = (const float*)d_in[15]; p.dbhh1 = (const float*)d_in[16];
  p.fcW   = (const float*)d_in[17]; p.fcb   = (const float*)d_in[18];
  p.out   = (float*)d_out;

  p.H   = (unsigned short*)d_ws;                 // 8 groups x 64 KB = 512 KB
  p.flg = (unsigned*)((char*)d_ws + 524288);     // 8 x 2 x 256 B flag blocks

  // Zero H (h(-1)=0 + zero pad rows m>=8) and flags every launch
  // (graph-capturable, replay-safe).
  hipMemsetAsync(d_ws, 0, 524288 + 4096, stream);

  lstm_persist<<<dim3(NWG), dim3(NTHR), 0, stream>>>(p);
}

// Round 14
// 15806.227 us; speedup vs baseline: 2.0729x; 1.5995x over previous
//
#include <hip/hip_runtime.h>
#include <stdint.h>

// LSTM seq2seq (B=64, S=2048, H=512, L=2), v14 = v12 (passed, 25.3ms) with the
// redundant-LLC-volume fix (NO transport changes; v13's XCD-local idea is
// abandoned after the vote-divergence deadlock):
//  * v12's ldA had every thread load its own A-frags: 64KB/WG/matrix of
//    uncached sc1 reads for a 16KB matrix (4 waves x identical data, half of
//    it zero-pad rows). 32MB LLC reads per encoder phase ~= the missing 2us.
//  * v14: H buffers store only the real m<8 rows (8KB/matrix). Each WG
//    cooperatively loads the 8KB ONCE (4x8B atomic loads/thread), stages into
//    LDS, then all waves ds_read_b128 their fragments. 8x less LLC volume.
//  * MFMA A-rows 8..15 receive copies of rows 0..7 (nn&7): harmless, since
//    D-rows 8..15 are never stored (lo4<2 guards on gwrite/y_s).
// Barrier, transport, weights, cell math bit-identical to v12.

#define NWG   256
#define NTHR  256
#define SEQ   2048
#define NH    512

typedef _Float16 half8v __attribute__((ext_vector_type(8)));
typedef float    f32x4  __attribute__((ext_vector_type(4)));

struct P {
  const float *x;
  const float *eWih0, *eWhh0, *ebih0, *ebhh0;
  const float *eWih1, *eWhh1, *ebih1, *ebhh1;
  const float *dWih0, *dWhh0, *dbih0, *dbhh0;
  const float *dWih1, *dWhh1, *dbih1, *dbhh1;
  const float *fcW, *fcb;
  float *out;
  unsigned short *H;   // 8 groups x {H0[2],H1[2]} x [64 ks4][8 m][8 e] fp16 (8KB each)
  unsigned *flg;       // 8 groups x 2 slots x 64 dwords; zeroed each launch
};

__device__ __forceinline__ uint64_t ldg64(const uint64_t* p) {
  return __hip_atomic_load(p, __ATOMIC_RELAXED, __HIP_MEMORY_SCOPE_AGENT);
}
__device__ __forceinline__ void stg64(uint64_t* p, uint64_t v) {
  __hip_atomic_store(p, v, __ATOMIC_RELAXED, __HIP_MEMORY_SCOPE_AGENT);
}
__device__ __forceinline__ float sigf(float v)   { return 1.f / (1.f + __expf(-v)); }
__device__ __forceinline__ float tanhf_(float v) { return 2.f * sigf(2.f * v) - 1.f; }

__global__ __launch_bounds__(NTHR, 1) void lstm_persist(P p) {
  __shared__ half8v wlds0[4][16][64];  // 64KB Whh0 slice [q][ks][lane]
  __shared__ half8v wlds2[4][16][64];  // 64KB Whh1 slice [q][ks][lane]
  __shared__ uint64_t stage[2][1024];  // 16KB: staged H matrices [sb][ks4*8+m)*2+seg]
  __shared__ half8v fcw_c[16][4];      // fcW broadcast B-frags
  __shared__ float  gate_s[2][4][8][17]; // [lay][q][m][c] padded
  __shared__ float  bias_s[2][4][16];  // current-stage bih+bhh [lay][q][c]
  __shared__ float  w0_s[4][16];       // current-stage Wih0 col [q][c]
  __shared__ float  c_st[2][16][9];    // fp32 cell state [lay][c][m]
  __shared__ float  h_tmp[2][16][9];   // fp32 h' staging  [lay][c][m]
  __shared__ float  x_s[8], y_s[8];
  __shared__ float  fcb_s;
  __shared__ unsigned done_s;

  const int wg   = blockIdx.x;
  const int g    = wg & 7;        // batch group: samples [8g, 8g+8)
  const int sl   = wg >> 3;       // hidden slice 0..31: cols [16sl, 16sl+16)
  const int tid  = threadIdx.x;
  const int lane = tid & 63;
  const int wv   = tid >> 6;      // wave = gate q (i,f,g,o)
  const int lo4  = lane >> 4;
  const int nn   = lane & 15;

  unsigned short* Hg = p.H + (size_t)g * 16384;       // 32KB/group in halfs
  unsigned short* H0p[2] = {Hg, Hg + 4096};
  unsigned short* H1p[2] = {Hg + 8192, Hg + 12288};
  unsigned epoch = 0;

  half8v w1[16];                  // Wih1 own-gate-rows B-frags (64 VGPR)

  // ---- private group barrier: packed flag stores + 16-lane pair poll ----
  auto arrive = [&]() {
    epoch++;
    __syncthreads();              // drains vmcnt(0): publishes complete at LLC
    if (tid == 0)
      __hip_atomic_store(p.flg + (g * 2 + (epoch & 1)) * 64 + sl, epoch,
                         __ATOMIC_RELAXED, __HIP_MEMORY_SCOPE_AGENT);
  };
  auto wait = [&]() {
    if (wv == 0) {
      if (lane < 16) {            // 2 flags per lane, one 8B load per iter
        const uint64_t tgt = (uint64_t)epoch * 0x100000001ull;
        const uint64_t* fp =
            (const uint64_t*)(p.flg + (g * 2 + (epoch & 1)) * 64) + lane;
        while (__hip_atomic_load(fp, __ATOMIC_RELAXED,
                                 __HIP_MEMORY_SCOPE_AGENT) != tgt) {}
      }
      if (lane == 0)
        __hip_atomic_store(&done_s, epoch, __ATOMIC_RELEASE,
                           __HIP_MEMORY_SCOPE_WORKGROUP);
    } else {
      float b0 = (float)tid, b1 = b0 + 1.f, b2 = b0 + 2.f, b3 = b0 + 3.f;
      while (__hip_atomic_load(&done_s, __ATOMIC_ACQUIRE,
                               __HIP_MEMORY_SCOPE_WORKGROUP) != epoch) {
#pragma unroll
        for (int i = 0; i < 16; ++i) {
          b0 = __builtin_fmaf(b0, 1.0000001f, 1.0e-7f);
          b1 = __builtin_fmaf(b1, 1.0000001f, 2.0e-7f);
          b2 = __builtin_fmaf(b2, 1.0000001f, 3.0e-7f);
          b3 = __builtin_fmaf(b3, 1.0000001f, 4.0e-7f);
        }
      }
      asm volatile("" :: "v"(b0), "v"(b1), "v"(b2), "v"(b3));
    }
    __builtin_amdgcn_fence(__ATOMIC_ACQUIRE, "workgroup");
    __syncthreads();
  };
  auto gbar = [&]() { arrive(); wait(); };

  // ---- cooperative H staging: 8KB matrix -> LDS (4x8B atomic loads/thread) ----
  auto stageH = [&](int sb, const unsigned short* Hm) {
    const uint64_t* bp = (const uint64_t*)Hm;
    uint64_t v0 = ldg64(bp + 0 * 256 + tid);
    uint64_t v1 = ldg64(bp + 1 * 256 + tid);
    uint64_t v2 = ldg64(bp + 2 * 256 + tid);
    uint64_t v3 = ldg64(bp + 3 * 256 + tid);
    stage[sb][0 * 256 + tid] = v0;
    stage[sb][1 * 256 + tid] = v1;
    stage[sb][2 * 256 + tid] = v2;
    stage[sb][3 * 256 + tid] = v3;
  };
  // A-fragment from stage: rows 8..15 mirror rows 0..7 (harmless, D-rows unused)
  auto frag = [&](int sb, int ks) -> half8v {
    return *(const half8v*)((const char*)&stage[sb][0] +
                            (((4 * ks + lo4) * 8 + (nn & 7)) << 4));
  };

  // ---- weight gathers (sigma: k = 32ks + 8*lo4 + e on BOTH A and B sides) ----
  auto loadW = [&](half8v (*wl)[16][64], const float* __restrict__ W) {
    for (int idx = tid; idx < 4096; idx += NTHR) {
      const int q = idx >> 10, ks = (idx >> 6) & 15, l = idx & 63;
      const int gr = 512 * q + 16 * sl + (l & 15);
      const float* base = W + (size_t)gr * NH + 32 * ks + 8 * (l >> 4);
      f32x4 wa, wb;
      __builtin_memcpy(&wa, base, 16);
      __builtin_memcpy(&wb, base + 4, 16);
      half8v h;
      h[0]=(_Float16)wa[0]; h[1]=(_Float16)wa[1]; h[2]=(_Float16)wa[2]; h[3]=(_Float16)wa[3];
      h[4]=(_Float16)wb[0]; h[5]=(_Float16)wb[1]; h[6]=(_Float16)wb[2]; h[7]=(_Float16)wb[3];
      wl[q][ks][l] = h;
    }
  };
  auto loadWV = [&](half8v* w, const float* __restrict__ W) {
    const int gr = 512 * wv + 16 * sl + nn;
    const float* base = W + (size_t)gr * NH + 8 * lo4;
#pragma unroll
    for (int ks = 0; ks < 16; ++ks) {
      f32x4 wa, wb;
      __builtin_memcpy(&wa, base + 32 * ks, 16);
      __builtin_memcpy(&wb, base + 32 * ks + 4, 16);
      half8v h;
      h[0]=(_Float16)wa[0]; h[1]=(_Float16)wa[1]; h[2]=(_Float16)wa[2]; h[3]=(_Float16)wa[3];
      h[4]=(_Float16)wb[0]; h[5]=(_Float16)wb[1]; h[6]=(_Float16)wb[2]; h[7]=(_Float16)wb[3];
      w[ks] = h;
    }
  };
  auto loadBias = [&](const float* bi0, const float* bh0, const float* bi1,
                      const float* bh1, const float* Wi0) {
    if (tid < 128) {
      const int lay = tid >> 6, q = (tid >> 4) & 3, c = tid & 15;
      const int gr = 512 * q + 16 * sl + c;
      bias_s[lay][q][c] = lay ? (bi1[gr] + bh1[gr]) : (bi0[gr] + bh0[gr]);
    }
    if (tid < 64) {
      const int q = tid >> 4, c = tid & 15;
      w0_s[q][c] = Wi0[512 * q + 16 * sl + c];
    }
  };

  auto mmL = [&](f32x4& a, int sb, half8v (*wl)[16][64]) {
#pragma unroll
    for (int ks = 0; ks < 16; ++ks)
      a = __builtin_amdgcn_mfma_f32_16x16x32_f16(frag(sb, ks), wl[wv][ks][lane], a, 0, 0, 0);
  };
  auto mmV = [&](f32x4& a, int sb, const half8v* w) {
#pragma unroll
    for (int ks = 0; ks < 16; ++ks)
      a = __builtin_amdgcn_mfma_f32_16x16x32_f16(frag(sb, ks), w[ks], a, 0, 0, 0);
  };
  auto mmFC = [&](f32x4& a, int sb) {
#pragma unroll
    for (int ks = 0; ks < 16; ++ks)
      a = __builtin_amdgcn_mfma_f32_16x16x32_f16(frag(sb, ks), fcw_c[ks][lo4], a, 0, 0, 0);
  };

  auto gwrite = [&](int lay, const f32x4& acc) {
    if (lo4 < 2) {
#pragma unroll
      for (int j = 0; j < 4; ++j) gate_s[lay][wv][4 * lo4 + j][nn] = acc[j];
    }
  };
  auto cellOne = [&](int lay, const float* inp8) {
    if (tid < 128) {
      const int c = tid & 15, m = tid >> 4;
      float g0 = gate_s[lay][0][m][c] + bias_s[lay][0][c];
      float g1 = gate_s[lay][1][m][c] + bias_s[lay][1][c];
      float g2 = gate_s[lay][2][m][c] + bias_s[lay][2][c];
      float g3 = gate_s[lay][3][m][c] + bias_s[lay][3][c];
      if (lay == 0) {
        const float xm = inp8[m];
        g0 += xm * w0_s[0][c]; g1 += xm * w0_s[1][c];
        g2 += xm * w0_s[2][c]; g3 += xm * w0_s[3][c];
      }
      const float i = sigf(g0), f = sigf(g1), gg = tanhf_(g2), o = sigf(g3);
      const float cn = f * c_st[lay][c][m] + i * gg;
      c_st[lay][c][m] = cn;
      h_tmp[lay][c][m] = o * tanhf_(cn);
    }
  };
  auto cellsEnc = [&](bool d0, bool d1) {
    const int lay = tid >> 7, u = tid & 127, c = u & 15, m = u >> 4;
    if (lay ? d1 : d0) {
      float g0 = gate_s[lay][0][m][c] + bias_s[lay][0][c];
      float g1 = gate_s[lay][1][m][c] + bias_s[lay][1][c];
      float g2 = gate_s[lay][2][m][c] + bias_s[lay][2][c];
      float g3 = gate_s[lay][3][m][c] + bias_s[lay][3][c];
      if (lay == 0) {
        const float xm = x_s[m];
        g0 += xm * w0_s[0][c]; g1 += xm * w0_s[1][c];
        g2 += xm * w0_s[2][c]; g3 += xm * w0_s[3][c];
      }
      const float i = sigf(g0), f = sigf(g1), gg = tanhf_(g2), o = sigf(g3);
      const float cn = f * c_st[lay][c][m] + i * gg;
      c_st[lay][c][m] = cn;
      h_tmp[lay][c][m] = o * tanhf_(cn);
    }
  };
  // publish own 16 cols x 8 samples (256B) into [64 ks4][8 m][8 e] layout
  auto publish = [&](int lay, unsigned short* Hpar) {
    if (tid < 32) {
      const int k4 = tid >> 4, m = (tid >> 1) & 7, seg = tid & 1;
      union { uint64_t u; _Float16 h[4]; } cv;
#pragma unroll
      for (int z = 0; z < 4; ++z)
        cv.h[z] = (_Float16)h_tmp[lay][8 * k4 + 4 * seg + z][m];
      stg64((uint64_t*)Hpar + ((size_t)(2 * sl + k4) * 8 + m) * 2 + seg, cv.u);
    }
  };

  // ================= init =================
  loadW(wlds0, p.eWhh0);
  loadW(wlds2, p.eWhh1);
  loadWV(w1, p.eWih1);
  loadBias(p.ebih0, p.ebhh0, p.ebih1, p.ebhh1, p.eWih0);
  if (tid < 64) {                 // fcW broadcast B-frag (same sigma)
    const int ks = tid >> 2, l4 = tid & 3;
    half8v h;
#pragma unroll
    for (int e = 0; e < 8; ++e) h[e] = (_Float16)p.fcW[32 * ks + 8 * l4 + e];
    fcw_c[ks][l4] = h;
  }
  if (tid == 0) { fcb_s = p.fcb[0]; done_s = 0; }
  for (int i = tid; i < 2 * 16 * 9; i += NTHR) {
    (&c_st[0][0][0])[i] = 0.f;
    (&h_tmp[0][0][0])[i] = 0.f;
  }
  // h0(-1)=0 (H0p[1]) and h1(-1)=0 (H1p[0]) come from the launch memset.
  gbar();                         // epoch 1: all init loads/memset settled

  // ================= encoder: L0(t) || L1(t-1), 1 barrier/phase =================
  for (int t = 0; t <= SEQ; ++t) {
    const int ri = (t + 1) & 1, wi = t & 1;
    const bool d0 = (t < SEQ), d1 = (t > 0);
    if (tid < 8 && d0) x_s[tid] = p.x[(size_t)(8 * g + tid) * SEQ + t];
    stageH(0, H0p[ri]);               // h0(t-1), cooperative 8KB
    if (d1) stageH(1, H1p[ri]);       // h1(t-2)
    __syncthreads();
    f32x4 a0 = {0.f, 0.f, 0.f, 0.f}, a1 = {0.f, 0.f, 0.f, 0.f};
    if (d0) mmL(a0, 0, wlds0);        // Whh0 . h0(t-1)
    if (d1) mmV(a1, 0, w1);           // Wih1 . h0(t-1)
    if (d1) mmL(a1, 1, wlds2);        // + Whh1 . h1(t-2)
    if (d0) gwrite(0, a0);
    if (d1) gwrite(1, a1);
    __syncthreads();
    cellsEnc(d0, d1);
    __syncthreads();
    if (d0) publish(0, H0p[wi]);
    if (d1) publish(1, H1p[wi]);
    gbar();
  }
  // leaves: h0_enc(2047) in H0p[1], h1_enc(2047) in H1p[0]

  // ================= enc -> dec transition =================
  loadW(wlds0, p.dWhh0);
  loadW(wlds2, p.dWhh1);
  loadWV(w1, p.dWih1);
  loadBias(p.dbih0, p.dbhh0, p.dbih1, p.dbhh1, p.dWih0);
  stageH(0, H0p[1]);                  // h0_enc
  __syncthreads();
  f32x4 accPre0 = {0.f, 0.f, 0.f, 0.f};
  mmL(accPre0, 0, wlds0);             // dWhh0 . h0_enc

  // ============ decoder: A(t)=fc+Whh1+cell0, B(t)=Wih1+cell1 [+Whh0 in wait] ====
  f32x4 aP1 = {0.f, 0.f, 0.f, 0.f};
  for (int t = 0; t < SEQ; ++t) {
    { // ---- A(t): reads h1(t-1) in H1p[t&1] ----
      stageH(1, H1p[t & 1]);
      __syncthreads();
      f32x4 a = {0.f, 0.f, 0.f, 0.f};
      mmL(a, 1, wlds2);               // Whh1 . h1(t-1)
      aP1 = a;
      if (wv == 0) {                  // y(t-1) = fc(h1(t-1))
        f32x4 afc = {0.f, 0.f, 0.f, 0.f};
        mmFC(afc, 1);
        if (nn == 0 && lo4 < 2) {
#pragma unroll
          for (int j = 0; j < 4; ++j)
            y_s[4 * lo4 + j] = (t == 0) ? 0.f : (afc[j] + fcb_s);
        }
      }
      gwrite(0, accPre0);             // Whh0 . h0(t-1) from previous B
      __syncthreads();
      cellOne(0, y_s);                // h0(t)
      __syncthreads();
      publish(0, H0p[t & 1]);
      arrive();
      // y output store inside the wait window: off the pre-flag drain path
      if (t > 0 && sl == 0 && tid < 8)
        p.out[(size_t)(8 * g + tid) * SEQ + (t - 1)] = y_s[tid];
      wait();
    }
    { // ---- B(t): reads h0(t) in H0p[t&1] ----
      stageH(0, H0p[t & 1]);
      __syncthreads();
      mmV(aP1, 0, w1);                // + Wih1 . h0(t)
      gwrite(1, aP1);
      __syncthreads();
      cellOne(1, nullptr);            // h1(t)
      __syncthreads();
      publish(1, H1p[(t + 1) & 1]);
      arrive();
      f32x4 a0n = {0.f, 0.f, 0.f, 0.f};
      mmL(a0n, 0, wlds0);             // Whh0 . h0(t) — stage[0] still valid
      wait();
      accPre0 = a0n;
    }
  }

  // ================= epilogue: y(2047) = fc(h1(2047)) in H1p[0] =================
  if (sl == 0) {
    stageH(1, H1p[0]);
    __syncthreads();
    if (wv == 0) {
      f32x4 afc = {0.f, 0.f, 0.f, 0.f};
      mmFC(afc, 1);
      if (nn == 0 && lo4 < 2) {
#pragma unroll
        for (int j = 0; j < 4; ++j) y_s[4 * lo4 + j] = afc[j] + fcb_s;
      }
    }
    __syncthreads();
    if (tid < 8) p.out[(size_t)(8 * g + tid) * SEQ + (SEQ - 1)] = y_s[tid];
  }
}

extern "C" void kernel_launch(void* const* d_in, const int* in_sizes, int n_in,
                              void* d_out, int out_size, void* d_ws, size_t ws_size,
                              hipStream_t stream) {
  (void)in_sizes; (void)n_in; (void)out_size; (void)ws_size;
  P p;
  p.x     = (const float*)d_in[0];
  p.eWih0 = (const float*)d_in[1];  p.eWhh0 = (const float*)d_in[2];
  p.ebih0 = (const float*)d_in[3];  p.ebhh0 = (const float*)d_in[4];
  p.eWih1 = (const float*)d_in[5];  p.eWhh1 = (const float*)d_in[6];
  p.ebih1 = (const float*)d_in[7];  p.ebhh1 = (const float*)d_in[8];
  p.dWih0 = (const float*)d_in[9];  p.dWhh0 = (const float*)d_in[10];
  p.dbih0 = (const float*)d_in[11]; p.dbhh0 = (const float*)d_in[12];
  p.dWih1 = (const float*)d_in[13]; p.dWhh1 = (const float*)d_in[14];
  p.dbih1 = (const float*)d_in[15]; p.dbhh1 = (const float*)d_in[16];
  p.fcW   = (const float*)d_in[17]; p.fcb   = (const float*)d_in[18];
  p.out   = (float*)d_out;

  p.H   = (unsigned short*)d_ws;                 // 8 groups x 32 KB = 256 KB
  p.flg = (unsigned*)((char*)d_ws + 262144);     // 8 x 2 x 256 B flag blocks

  // Zero H (h(-1)=0) and flags every launch (graph-capturable, replay-safe).
  hipMemsetAsync(d_ws, 0, 262144 + 4096, stream);

  lstm_persist<<<dim3(NWG), dim3(NTHR), 0, stream>>>(p);
}

// Round 15
// 14412.010 us; speedup vs baseline: 2.2735x; 1.0967x over previous
//
#include <hip/hip_runtime.h>
#include <stdint.h>

// LSTM seq2seq (B=64, S=2048, H=512, L=2), v15 = v14 (passed, 15.8ms) + two
// phase-tail cuts (transport/math untouched):
//  * flags spread to one 32B-strided region per WG (was 32 dwords packed in
//    ONE 128B line): the 32 arrive-stores land in parallel LLC banks instead
//    of serializing against the poll storm; poll = 32 lanes x own dword
//    (v2-proven __all loop).
//  * publish direct-from-register: cell threads pack fp16 pairs via one
//    __shfl_xor and even-c lanes issue 4B relaxed-atomic stores straight to
//    H (drops h_tmp LDS round trip + one __syncthreads per phase).
// Topology: 8 groups (wg&7) x 32 WGs (sl=wg>>3); 8KB H matrices (m<8 rows),
// cooperative LDS staging; Whh0+Whh1 LDS, Wih1 VGPR; fc-as-broadcast-MFMA;
// fp32 cell state; agent-scope relaxed-atomic transport; DVFS burn waits.

#define NWG   256
#define NTHR  256
#define SEQ   2048
#define NH    512

typedef _Float16 half8v __attribute__((ext_vector_type(8)));
typedef float    f32x4  __attribute__((ext_vector_type(4)));

struct P {
  const float *x;
  const float *eWih0, *eWhh0, *ebih0, *ebhh0;
  const float *eWih1, *eWhh1, *ebih1, *ebhh1;
  const float *dWih0, *dWhh0, *dbih0, *dbhh0;
  const float *dWih1, *dWhh1, *dbih1, *dbhh1;
  const float *fcW, *fcb;
  float *out;
  unsigned short *H;   // 8 groups x {H0[2],H1[2]} x [64 ks4][8 m][8 e] fp16 (8KB each)
  unsigned *flg;       // 8 g x 2 slots x 32 wg x 32B; zeroed each launch
};

__device__ __forceinline__ uint64_t ldg64(const uint64_t* p) {
  return __hip_atomic_load(p, __ATOMIC_RELAXED, __HIP_MEMORY_SCOPE_AGENT);
}
__device__ __forceinline__ void stg32(unsigned* p, unsigned v) {
  __hip_atomic_store(p, v, __ATOMIC_RELAXED, __HIP_MEMORY_SCOPE_AGENT);
}
__device__ __forceinline__ float sigf(float v)   { return 1.f / (1.f + __expf(-v)); }
__device__ __forceinline__ float tanhf_(float v) { return 2.f * sigf(2.f * v) - 1.f; }

__global__ __launch_bounds__(NTHR, 1) void lstm_persist(P p) {
  __shared__ half8v wlds0[4][16][64];  // 64KB Whh0 slice [q][ks][lane]
  __shared__ half8v wlds2[4][16][64];  // 64KB Whh1 slice [q][ks][lane]
  __shared__ uint64_t stage[2][1024];  // 16KB staged H matrices
  __shared__ half8v fcw_c[16][4];      // fcW broadcast B-frags
  __shared__ float  gate_s[2][4][8][17]; // [lay][q][m][c] padded
  __shared__ float  bias_s[2][4][16];  // current-stage bih+bhh [lay][q][c]
  __shared__ float  w0_s[4][16];       // current-stage Wih0 col [q][c]
  __shared__ float  c_st[2][16][9];    // fp32 cell state [lay][c][m]
  __shared__ float  x_s[8], y_s[8];
  __shared__ float  fcb_s;
  __shared__ unsigned done_s;

  const int wg   = blockIdx.x;
  const int g    = wg & 7;        // batch group: samples [8g, 8g+8)
  const int sl   = wg >> 3;       // hidden slice 0..31: cols [16sl, 16sl+16)
  const int tid  = threadIdx.x;
  const int lane = tid & 63;
  const int wv   = tid >> 6;      // wave = gate q (i,f,g,o)
  const int lo4  = lane >> 4;
  const int nn   = lane & 15;

  unsigned short* Hg = p.H + (size_t)g * 16384;       // 32KB/group in halfs
  unsigned short* H0p[2] = {Hg, Hg + 4096};
  unsigned short* H1p[2] = {Hg + 8192, Hg + 12288};
  unsigned epoch = 0;

  half8v w1[16];                  // Wih1 own-gate-rows B-frags (64 VGPR)

  // ---- barrier: per-WG 32B-strided flag regions + 32-lane parallel poll ----
  auto arrive = [&]() {
    epoch++;
    __syncthreads();              // drains vmcnt(0): publishes complete at LLC
    if (tid == 0)
      stg32(p.flg + ((size_t)(g * 2 + (epoch & 1)) * 32 + sl) * 8, epoch);
  };
  auto wait = [&]() {
    if (wv == 0) {
      const unsigned* base = p.flg + (size_t)(g * 2 + (epoch & 1)) * 256;
      bool ok = (lane >= 32);
      while (!__all(ok)) {
        if (!ok)
          ok = (__hip_atomic_load(base + lane * 8, __ATOMIC_RELAXED,
                                  __HIP_MEMORY_SCOPE_AGENT) == epoch);
      }
      if (lane == 0)
        __hip_atomic_store(&done_s, epoch, __ATOMIC_RELEASE,
                           __HIP_MEMORY_SCOPE_WORKGROUP);
    } else {
      float b0 = (float)tid, b1 = b0 + 1.f, b2 = b0 + 2.f, b3 = b0 + 3.f;
      while (__hip_atomic_load(&done_s, __ATOMIC_ACQUIRE,
                               __HIP_MEMORY_SCOPE_WORKGROUP) != epoch) {
#pragma unroll
        for (int i = 0; i < 8; ++i) {
          b0 = __builtin_fmaf(b0, 1.0000001f, 1.0e-7f);
          b1 = __builtin_fmaf(b1, 1.0000001f, 2.0e-7f);
          b2 = __builtin_fmaf(b2, 1.0000001f, 3.0e-7f);
          b3 = __builtin_fmaf(b3, 1.0000001f, 4.0e-7f);
        }
      }
      asm volatile("" :: "v"(b0), "v"(b1), "v"(b2), "v"(b3));
    }
    __builtin_amdgcn_fence(__ATOMIC_ACQUIRE, "workgroup");
    __syncthreads();
  };
  auto gbar = [&]() { arrive(); wait(); };

  // ---- cooperative H staging: 8KB matrix -> LDS (4x8B atomic loads/thread) ----
  auto stageH = [&](int sb, const unsigned short* Hm) {
    const uint64_t* bp = (const uint64_t*)Hm;
    uint64_t v0 = ldg64(bp + 0 * 256 + tid);
    uint64_t v1 = ldg64(bp + 1 * 256 + tid);
    uint64_t v2 = ldg64(bp + 2 * 256 + tid);
    uint64_t v3 = ldg64(bp + 3 * 256 + tid);
    stage[sb][0 * 256 + tid] = v0;
    stage[sb][1 * 256 + tid] = v1;
    stage[sb][2 * 256 + tid] = v2;
    stage[sb][3 * 256 + tid] = v3;
  };
  // A-fragment from stage: rows 8..15 mirror rows 0..7 (harmless, D-rows unused)
  auto frag = [&](int sb, int ks) -> half8v {
    return *(const half8v*)((const char*)&stage[sb][0] +
                            (((4 * ks + lo4) * 8 + (nn & 7)) << 4));
  };

  // ---- weight gathers (sigma: k = 32ks + 8*lo4 + e on BOTH A and B sides) ----
  auto loadW = [&](half8v (*wl)[16][64], const float* __restrict__ W) {
    for (int idx = tid; idx < 4096; idx += NTHR) {
      const int q = idx >> 10, ks = (idx >> 6) & 15, l = idx & 63;
      const int gr = 512 * q + 16 * sl + (l & 15);
      const float* base = W + (size_t)gr * NH + 32 * ks + 8 * (l >> 4);
      f32x4 wa, wb;
      __builtin_memcpy(&wa, base, 16);
      __builtin_memcpy(&wb, base + 4, 16);
      half8v h;
      h[0]=(_Float16)wa[0]; h[1]=(_Float16)wa[1]; h[2]=(_Float16)wa[2]; h[3]=(_Float16)wa[3];
      h[4]=(_Float16)wb[0]; h[5]=(_Float16)wb[1]; h[6]=(_Float16)wb[2]; h[7]=(_Float16)wb[3];
      wl[q][ks][l] = h;
    }
  };
  auto loadWV = [&](half8v* w, const float* __restrict__ W) {
    const int gr = 512 * wv + 16 * sl + nn;
    const float* base = W + (size_t)gr * NH + 8 * lo4;
#pragma unroll
    for (int ks = 0; ks < 16; ++ks) {
      f32x4 wa, wb;
      __builtin_memcpy(&wa, base + 32 * ks, 16);
      __builtin_memcpy(&wb, base + 32 * ks + 4, 16);
      half8v h;
      h[0]=(_Float16)wa[0]; h[1]=(_Float16)wa[1]; h[2]=(_Float16)wa[2]; h[3]=(_Float16)wa[3];
      h[4]=(_Float16)wb[0]; h[5]=(_Float16)wb[1]; h[6]=(_Float16)wb[2]; h[7]=(_Float16)wb[3];
      w[ks] = h;
    }
  };
  auto loadBias = [&](const float* bi0, const float* bh0, const float* bi1,
                      const float* bh1, const float* Wi0) {
    if (tid < 128) {
      const int lay = tid >> 6, q = (tid >> 4) & 3, c = tid & 15;
      const int gr = 512 * q + 16 * sl + c;
      bias_s[lay][q][c] = lay ? (bi1[gr] + bh1[gr]) : (bi0[gr] + bh0[gr]);
    }
    if (tid < 64) {
      const int q = tid >> 4, c = tid & 15;
      w0_s[q][c] = Wi0[512 * q + 16 * sl + c];
    }
  };

  auto mmL = [&](f32x4& a, int sb, half8v (*wl)[16][64]) {
#pragma unroll
    for (int ks = 0; ks < 16; ++ks)
      a = __builtin_amdgcn_mfma_f32_16x16x32_f16(frag(sb, ks), wl[wv][ks][lane], a, 0, 0, 0);
  };
  auto mmV = [&](f32x4& a, int sb, const half8v* w) {
#pragma unroll
    for (int ks = 0; ks < 16; ++ks)
      a = __builtin_amdgcn_mfma_f32_16x16x32_f16(frag(sb, ks), w[ks], a, 0, 0, 0);
  };
  auto mmFC = [&](f32x4& a, int sb) {
#pragma unroll
    for (int ks = 0; ks < 16; ++ks)
      a = __builtin_amdgcn_mfma_f32_16x16x32_f16(frag(sb, ks), fcw_c[ks][lo4], a, 0, 0, 0);
  };

  auto gwrite = [&](int lay, const f32x4& acc) {
    if (lo4 < 2) {
#pragma unroll
      for (int j = 0; j < 4; ++j) gate_s[lay][wv][4 * lo4 + j][nn] = acc[j];
    }
  };
  // cell body for one (lay,c,m): gates -> cn,hn; hn published directly:
  // pack fp16 pair with lane^1 partner, even-c lanes store 4B.
  auto cellStore = [&](int lay, int c, int m, const float* inp8,
                       unsigned short* Hpar) {
    float g0 = gate_s[lay][0][m][c] + bias_s[lay][0][c];
    float g1 = gate_s[lay][1][m][c] + bias_s[lay][1][c];
    float g2 = gate_s[lay][2][m][c] + bias_s[lay][2][c];
    float g3 = gate_s[lay][3][m][c] + bias_s[lay][3][c];
    if (lay == 0) {
      const float xm = inp8[m];
      g0 += xm * w0_s[0][c]; g1 += xm * w0_s[1][c];
      g2 += xm * w0_s[2][c]; g3 += xm * w0_s[3][c];
    }
    const float i = sigf(g0), f = sigf(g1), gg = tanhf_(g2), o = sigf(g3);
    const float cn = f * c_st[lay][c][m] + i * gg;
    c_st[lay][c][m] = cn;
    const float hn = o * tanhf_(cn);
    union { unsigned u; _Float16 h; } cv;
    cv.u = 0; cv.h = (_Float16)hn;
    const unsigned partner = (unsigned)__shfl_xor((int)cv.u, 1, 64);
    if ((c & 1) == 0) {
      unsigned* dst = (unsigned*)Hpar +
                      ((size_t)(2 * sl + (c >> 3)) * 8 + m) * 4 + ((c & 7) >> 1);
      stg32(dst, cv.u | (partner << 16));
    }
  };
  auto cellsEnc = [&](bool d0, bool d1, unsigned short* D0, unsigned short* D1) {
    const int lay = tid >> 7, u = tid & 127, c = u & 15, m = u >> 4;
    if (lay ? d1 : d0)
      cellStore(lay, c, m, x_s, lay ? D1 : D0);
  };
  auto cellOne = [&](int lay, const float* inp8, unsigned short* D) {
    if (tid < 128) {
      const int c = tid & 15, m = tid >> 4;
      cellStore(lay, c, m, inp8, D);
    }
  };

  // ================= init =================
  loadW(wlds0, p.eWhh0);
  loadW(wlds2, p.eWhh1);
  loadWV(w1, p.eWih1);
  loadBias(p.ebih0, p.ebhh0, p.ebih1, p.ebhh1, p.eWih0);
  if (tid < 64) {                 // fcW broadcast B-frag (same sigma)
    const int ks = tid >> 2, l4 = tid & 3;
    half8v h;
#pragma unroll
    for (int e = 0; e < 8; ++e) h[e] = (_Float16)p.fcW[32 * ks + 8 * l4 + e];
    fcw_c[ks][l4] = h;
  }
  if (tid == 0) { fcb_s = p.fcb[0]; done_s = 0; }
  for (int i = tid; i < 2 * 16 * 9; i += NTHR) (&c_st[0][0][0])[i] = 0.f;
  // h0(-1)=0 (H0p[1]) and h1(-1)=0 (H1p[0]) come from the launch memset.
  gbar();                         // epoch 1: all init loads/memset settled

  // ================= encoder: L0(t) || L1(t-1), 1 barrier/phase =================
  for (int t = 0; t <= SEQ; ++t) {
    const int ri = (t + 1) & 1, wi = t & 1;
    const bool d0 = (t < SEQ), d1 = (t > 0);
    if (tid < 8 && d0) x_s[tid] = p.x[(size_t)(8 * g + tid) * SEQ + t];
    stageH(0, H0p[ri]);               // h0(t-1), cooperative 8KB
    if (d1) stageH(1, H1p[ri]);       // h1(t-2)
    __syncthreads();
    f32x4 a0 = {0.f, 0.f, 0.f, 0.f}, a1 = {0.f, 0.f, 0.f, 0.f};
    if (d0) mmL(a0, 0, wlds0);        // Whh0 . h0(t-1)
    if (d1) mmV(a1, 0, w1);           // Wih1 . h0(t-1)
    if (d1) mmL(a1, 1, wlds2);        // + Whh1 . h1(t-2)
    if (d0) gwrite(0, a0);
    if (d1) gwrite(1, a1);
    __syncthreads();
    cellsEnc(d0, d1, H0p[wi], H1p[wi]);   // cells + direct publish
    gbar();
  }
  // leaves: h0_enc(2047) in H0p[1], h1_enc(2047) in H1p[0]

  // ================= enc -> dec transition =================
  loadW(wlds0, p.dWhh0);
  loadW(wlds2, p.dWhh1);
  loadWV(w1, p.dWih1);
  loadBias(p.dbih0, p.dbhh0, p.dbih1, p.dbhh1, p.dWih0);
  stageH(0, H0p[1]);                  // h0_enc
  __syncthreads();
  f32x4 accPre0 = {0.f, 0.f, 0.f, 0.f};
  mmL(accPre0, 0, wlds0);             // dWhh0 . h0_enc

  // ============ decoder: A(t)=fc+Whh1+cell0, B(t)=Wih1+cell1 [+Whh0 in wait] ====
  f32x4 aP1 = {0.f, 0.f, 0.f, 0.f};
  for (int t = 0; t < SEQ; ++t) {
    { // ---- A(t): reads h1(t-1) in H1p[t&1] ----
      stageH(1, H1p[t & 1]);
      __syncthreads();
      f32x4 a = {0.f, 0.f, 0.f, 0.f};
      mmL(a, 1, wlds2);               // Whh1 . h1(t-1)
      aP1 = a;
      if (wv == 0) {                  // y(t-1) = fc(h1(t-1))
        f32x4 afc = {0.f, 0.f, 0.f, 0.f};
        mmFC(afc, 1);
        if (nn == 0 && lo4 < 2) {
#pragma unroll
          for (int j = 0; j < 4; ++j)
            y_s[4 * lo4 + j] = (t == 0) ? 0.f : (afc[j] + fcb_s);
        }
      }
      gwrite(0, accPre0);             // Whh0 . h0(t-1) from previous B
      __syncthreads();
      cellOne(0, y_s, H0p[t & 1]);    // h0(t) + direct publish
      arrive();
      // y output store inside the wait window: off the pre-flag drain path
      if (t > 0 && sl == 0 && tid < 8)
        p.out[(size_t)(8 * g + tid) * SEQ + (t - 1)] = y_s[tid];
      wait();
    }
    { // ---- B(t): reads h0(t) in H0p[t&1] ----
      stageH(0, H0p[t & 1]);
      __syncthreads();
      mmV(aP1, 0, w1);                // + Wih1 . h0(t)
      gwrite(1, aP1);
      __syncthreads();
      cellOne(1, nullptr, H1p[(t + 1) & 1]);  // h1(t) + direct publish
      arrive();
      f32x4 a0n = {0.f, 0.f, 0.f, 0.f};
      mmL(a0n, 0, wlds0);             // Whh0 . h0(t) — stage[0] still valid
      wait();
      accPre0 = a0n;
    }
  }

  // ================= epilogue: y(2047) = fc(h1(2047)) in H1p[0] =================
  if (sl == 0) {
    stageH(1, H1p[0]);
    __syncthreads();
    if (wv == 0) {
      f32x4 afc = {0.f, 0.f, 0.f, 0.f};
      mmFC(afc, 1);
      if (nn == 0 && lo4 < 2) {
#pragma unroll
        for (int j = 0; j < 4; ++j) y_s[4 * lo4 + j] = afc[j] + fcb_s;
      }
    }
    __syncthreads();
    if (tid < 8) p.out[(size_t)(8 * g + tid) * SEQ + (SEQ - 1)] = y_s[tid];
  }
}

extern "C" void kernel_launch(void* const* d_in, const int* in_sizes, int n_in,
                              void* d_out, int out_size, void* d_ws, size_t ws_size,
                              hipStream_t stream) {
  (void)in_sizes; (void)n_in; (void)out_size; (void)ws_size;
  P p;
  p.x     = (const float*)d_in[0];
  p.eWih0 = (const float*)d_in[1];  p.eWhh0 = (const float*)d_in[2];
  p.ebih0 = (const float*)d_in[3];  p.ebhh0 = (const float*)d_in[4];
  p.eWih1 = (const float*)d_in[5];  p.eWhh1 = (const float*)d_in[6];
  p.ebih1 = (const float*)d_in[7];  p.ebhh1 = (const float*)d_in[8];
  p.dWih0 = (const float*)d_in[9];  p.dWhh0 = (const float*)d_in[10];
  p.dbih0 = (const float*)d_in[11]; p.dbhh0 = (const float*)d_in[12];
  p.dWih1 = (const float*)d_in[13]; p.dWhh1 = (const float*)d_in[14];
  p.dbih1 = (const float*)d_in[15]; p.dbhh1 = (const float*)d_in[16];
  p.fcW   = (const float*)d_in[17]; p.fcb   = (const float*)d_in[18];
  p.out   = (float*)d_out;

  p.H   = (unsigned short*)d_ws;                 // 8 groups x 32 KB = 256 KB
  p.flg = (unsigned*)((char*)d_ws + 262144);     // 8 x 2 x 32 x 32 B = 16 KB

  // Zero H (h(-1)=0) and flags every launch (graph-capturable, replay-safe).
  hipMemsetAsync(d_ws, 0, 262144 + 16384, stream);

  lstm_persist<<<dim3(NWG), dim3(NTHR), 0, stream>>>(p);
}